// Round 1
// baseline (4871.418 us; speedup 1.0000x reference)
//
#include <hip/hip_runtime.h>

#define NN 50000
#define NEDGE 400000
constexpr float LN_EPS = 1e-5f;

// ---------------- degree / dinv ----------------
__global__ void k_deg(const int* __restrict__ dst, float* __restrict__ deg) {
  int e = blockIdx.x * blockDim.x + threadIdx.x;
  if (e < NEDGE) unsafeAtomicAdd(&deg[dst[e]], 1.0f);
}

__global__ void k_dinv(float* __restrict__ deg) {
  int i = blockIdx.x * blockDim.x + threadIdx.x;
  if (i < NN) deg[i] = rsqrtf(deg[i] + 1.0f);
}

// ---------------- self-loop init: agg = h * dinv^2 (full overwrite) ----------------
template<int F>
__global__ void k_selfinit(const float* __restrict__ h, const float* __restrict__ dinv,
                           float* __restrict__ agg) {
  constexpr int V = F / 4;
  int idx = blockIdx.x * blockDim.x + threadIdx.x;
  if (idx >= NN * V) return;
  int row = idx / V;  // pow2 divide
  float d = dinv[row];
  float s = d * d;
  float4 v = reinterpret_cast<const float4*>(h)[idx];
  v.x *= s; v.y *= s; v.z *= s; v.w *= s;
  reinterpret_cast<float4*>(agg)[idx] = v;
}

// ---------------- edge scatter: agg[dst] += h[src] * dinv[src]*dinv[dst] ----------------
template<int F>
__global__ void k_scatter(const int* __restrict__ src, const int* __restrict__ dst,
                          const float* __restrict__ dinv, const float* __restrict__ h,
                          float* __restrict__ agg) {
  constexpr int LPE = F / 4;       // lanes per edge (float4 each)
  constexpr int EPB = 256 / LPE;   // edges per block
  const int t = threadIdx.x;
  const int e = blockIdx.x * EPB + (t / LPE);
  if (e >= NEDGE) return;
  const int lane = t % LPE;
  const int s = src[e], d = dst[e];
  const float w = dinv[s] * dinv[d];
  const float4 v = reinterpret_cast<const float4*>(h + (size_t)s * F)[lane];
  float* out = agg + (size_t)d * F + lane * 4;
  unsafeAtomicAdd(out + 0, v.x * w);
  unsafeAtomicAdd(out + 1, v.y * w);
  unsafeAtomicAdd(out + 2, v.z * w);
  unsafeAtomicAdd(out + 3, v.w * w);
}

// ---------------- fused GEMM (+bias +LN +ReLU) ----------------
// block = F threads (one per output column), R rows per block.
template<int K, int F, bool BIAS, bool LNORM, bool RELU>
__global__ __launch_bounds__(F) void k_gemm(
    const float* __restrict__ P, const float* __restrict__ W,
    const float* __restrict__ bias, const float* __restrict__ gamma,
    const float* __restrict__ beta, float* __restrict__ Out) {
  constexpr int R = 16;
  constexpr int NW = F / 64;
  const int f = threadIdx.x;
  const int row0 = blockIdx.x * R;

  float acc[R];
#pragma unroll
  for (int r = 0; r < R; ++r) acc[r] = 0.f;

  for (int kb = 0; kb < K; kb += 4) {
    const float w0 = W[(kb + 0) * F + f];
    const float w1 = W[(kb + 1) * F + f];
    const float w2 = W[(kb + 2) * F + f];
    const float w3 = W[(kb + 3) * F + f];
#pragma unroll
    for (int r = 0; r < R; ++r) {
      const float4 pv = *reinterpret_cast<const float4*>(&P[(size_t)(row0 + r) * K + kb]);
      acc[r] = fmaf(pv.w, w3, fmaf(pv.z, w2, fmaf(pv.y, w1, fmaf(pv.x, w0, acc[r]))));
    }
  }

  if constexpr (BIAS) {
    const float b = bias[f];
#pragma unroll
    for (int r = 0; r < R; ++r) acc[r] += b;
  }

  if constexpr (LNORM) {
    __shared__ float redS[NW][R];
    __shared__ float redQ[NW][R];
    const int wid = f >> 6, lane = f & 63;
#pragma unroll
    for (int r = 0; r < R; ++r) {
      float s = acc[r], q = acc[r] * acc[r];
#pragma unroll
      for (int off = 32; off > 0; off >>= 1) {
        s += __shfl_xor(s, off);
        q += __shfl_xor(q, off);
      }
      if (lane == 0) { redS[wid][r] = s; redQ[wid][r] = q; }
    }
    __syncthreads();
    const float gm = gamma[f], bt = beta[f];
#pragma unroll
    for (int r = 0; r < R; ++r) {
      float s = 0.f, q = 0.f;
#pragma unroll
      for (int w = 0; w < NW; ++w) { s += redS[w][r]; q += redQ[w][r]; }
      const float mean = s * (1.0f / F);
      const float var = q * (1.0f / F) - mean * mean;
      const float inv = rsqrtf(var + LN_EPS);
      float o = (acc[r] - mean) * inv * gm + bt;
      if constexpr (RELU) o = fmaxf(o, 0.f);
      Out[(size_t)(row0 + r) * F + f] = o;
    }
  } else {
#pragma unroll
    for (int r = 0; r < R; ++r) Out[(size_t)(row0 + r) * F + f] = acc[r];
  }
}

// ---------------- final bias + LN, in place on d_out (F=128) ----------------
__global__ void k_ln_final(float* __restrict__ io, const float* __restrict__ bias,
                           const float* __restrict__ g, const float* __restrict__ be) {
  const int row = blockIdx.x * 4 + (threadIdx.x >> 6);
  if (row >= NN) return;
  const int lane = threadIdx.x & 63;
  float2* rowp = reinterpret_cast<float2*>(io + (size_t)row * 128);
  float2 v = rowp[lane];
  const float2 bv = reinterpret_cast<const float2*>(bias)[lane];
  const float a0 = v.x + bv.x, a1 = v.y + bv.y;
  float s = a0 + a1, q = a0 * a0 + a1 * a1;
#pragma unroll
  for (int off = 32; off > 0; off >>= 1) {
    s += __shfl_xor(s, off);
    q += __shfl_xor(q, off);
  }
  const float mean = s * (1.0f / 128.0f);
  const float var = q * (1.0f / 128.0f) - mean * mean;
  const float inv = rsqrtf(var + LN_EPS);
  const float2 gv = reinterpret_cast<const float2*>(g)[lane];
  const float2 bev = reinterpret_cast<const float2*>(be)[lane];
  float2 o;
  o.x = (a0 - mean) * inv * gv.x + bev.x;
  o.y = (a1 - mean) * inv * gv.y + bev.y;
  rowp[lane] = o;
}

extern "C" void kernel_launch(void* const* d_in, const int* in_sizes, int n_in,
                              void* d_out, int out_size, void* d_ws, size_t ws_size,
                              hipStream_t stream) {
  const float* x   = (const float*)d_in[0];
  const int*   ei  = (const int*)d_in[1];
  const float* W1  = (const float*)d_in[2];
  const float* b1  = (const float*)d_in[3];
  const float* W2  = (const float*)d_in[4];
  const float* b2  = (const float*)d_in[5];
  const float* W3  = (const float*)d_in[6];
  const float* b3  = (const float*)d_in[7];
  const float* W4  = (const float*)d_in[8];
  const float* b4  = (const float*)d_in[9];
  const float* g1  = (const float*)d_in[10];
  const float* be1 = (const float*)d_in[11];
  const float* g2  = (const float*)d_in[12];
  const float* be2 = (const float*)d_in[13];
  const float* g3  = (const float*)d_in[14];
  const float* be3 = (const float*)d_in[15];
  const float* g4  = (const float*)d_in[16];
  const float* be4 = (const float*)d_in[17];

  const int* src = ei;          // edge_index[0]
  const int* dst = ei + NEDGE;  // edge_index[1]

  float* dinv = (float*)d_ws;                                  // NN floats
  float* bufA = (float*)((char*)d_ws + (256 * 1024));          // NN*256 floats
  float* bufB = bufA + (size_t)NN * 256;                       // NN*256 floats
  float* out  = (float*)d_out;                                 // NN*128 floats

  // degree -> dinv
  hipMemsetAsync(dinv, 0, NN * sizeof(float), stream);
  k_deg<<<(NEDGE + 255) / 256, 256, 0, stream>>>(dst, dinv);
  k_dinv<<<(NN + 255) / 256, 256, 0, stream>>>(dinv);

  // ---- Layer 1: aggregate x (F=128) -> GEMM 128->256 + LN + ReLU ----
  k_selfinit<128><<<(NN * 32 + 255) / 256, 256, 0, stream>>>(x, dinv, bufA);
  k_scatter<128><<<(NEDGE + 7) / 8, 256, 0, stream>>>(src, dst, dinv, x, bufA);
  k_gemm<128, 256, true, true, true><<<NN / 16, 256, 0, stream>>>(bufA, W1, b1, g1, be1, bufB);

  // ---- Layer 2: aggregate (F=256) -> GEMM 256->256 + LN + ReLU ----
  k_selfinit<256><<<(NN * 64 + 255) / 256, 256, 0, stream>>>(bufB, dinv, bufA);
  k_scatter<256><<<(NEDGE + 3) / 4, 256, 0, stream>>>(src, dst, dinv, bufB, bufA);
  k_gemm<256, 256, true, true, true><<<NN / 16, 256, 0, stream>>>(bufA, W2, b2, g2, be2, bufB);

  // ---- Layer 3 ----
  k_selfinit<256><<<(NN * 64 + 255) / 256, 256, 0, stream>>>(bufB, dinv, bufA);
  k_scatter<256><<<(NEDGE + 3) / 4, 256, 0, stream>>>(src, dst, dinv, bufB, bufA);
  k_gemm<256, 256, true, true, true><<<NN / 16, 256, 0, stream>>>(bufA, W3, b3, g3, be3, bufB);

  // ---- Layer 4: transform first (256->128, no bias), aggregate into d_out, bias+LN ----
  k_gemm<256, 128, false, false, false><<<NN / 16, 128, 0, stream>>>(bufB, W4, nullptr, nullptr, nullptr, bufA);
  k_selfinit<128><<<(NN * 32 + 255) / 256, 256, 0, stream>>>(bufA, dinv, out);
  k_scatter<128><<<(NEDGE + 7) / 8, 256, 0, stream>>>(src, dst, dinv, bufA, out);
  k_ln_final<<<(NN + 3) / 4, 256, 0, stream>>>(out, b4, g4, be4);
}

// Round 2
// 1165.897 us; speedup vs baseline: 4.1783x; 4.1783x over previous
//
#include <hip/hip_runtime.h>

#define NN 50000
#define NEDGE 400000
constexpr float LN_EPS = 1e-5f;

// ---------------- CSR build ----------------
__global__ void k_count(const int* __restrict__ dst, int* __restrict__ cnt) {
  int e = blockIdx.x * blockDim.x + threadIdx.x;
  if (e < NEDGE) atomicAdd(&cnt[dst[e]], 1);
}

__global__ void k_dinv(const int* __restrict__ cnt, float* __restrict__ dinv) {
  int i = blockIdx.x * blockDim.x + threadIdx.x;
  if (i < NN) dinv[i] = rsqrtf((float)cnt[i] + 1.0f);
}

// single-block exclusive scan of cnt[NN] -> rowptr[NN+1]
__global__ __launch_bounds__(1024) void k_scan(const int* __restrict__ cnt,
                                               int* __restrict__ rowptr) {
  constexpr int CH = (NN + 1023) / 1024;  // 49 elems per thread
  const int t = threadIdx.x;
  const int base = t * CH;
  int s = 0;
#pragma unroll
  for (int i = 0; i < CH; ++i) {
    int idx = base + i;
    if (idx < NN) s += cnt[idx];
  }
  const int lane = t & 63, wid = t >> 6;
  int inc = s;
  for (int off = 1; off < 64; off <<= 1) {
    int y = __shfl_up(inc, off);
    if (lane >= off) inc += y;
  }
  __shared__ int wsum[16];
  __shared__ int woff[16];
  if (lane == 63) wsum[wid] = inc;
  __syncthreads();
  if (t == 0) {
    int run = 0;
    for (int w = 0; w < 16; ++w) { woff[w] = run; run += wsum[w]; }
  }
  __syncthreads();
  int run = woff[wid] + inc - s;  // exclusive prefix for this thread's chunk
  for (int i = 0; i < CH; ++i) {
    int idx = base + i;
    if (idx < NN) { rowptr[idx] = run; run += cnt[idx]; }
  }
  if (t == 1023) rowptr[NN] = run;  // base > NN for t=1023 -> run == total
}

__global__ void k_fill(const int* __restrict__ src, const int* __restrict__ dst,
                       const int* __restrict__ rowptr, int* __restrict__ fill,
                       int* __restrict__ eidx) {
  int e = blockIdx.x * blockDim.x + threadIdx.x;
  if (e >= NEDGE) return;
  const int d = dst[e];
  const int p = rowptr[d] + atomicAdd(&fill[d], 1);
  eidx[p] = src[e];
}

// ---------------- gather aggregation: out[n] = h[n]*dinv[n]^2 + sum_e h[src]*dinv[src]*dinv[n]
// one wave per node; lane owns F/64 contiguous floats
template<int F>
__global__ __launch_bounds__(256) void k_gather(const int* __restrict__ rowptr,
                                                const int* __restrict__ eidx,
                                                const float* __restrict__ dinv,
                                                const float* __restrict__ h,
                                                float* __restrict__ out) {
  constexpr int VE = F / 64;  // 4 (F=256) or 2 (F=128)
  const int n = blockIdx.x * 4 + (threadIdx.x >> 6);
  if (n >= NN) return;
  const int lane = threadIdx.x & 63;
  const float dn = dinv[n];
  const int beg = rowptr[n], end = rowptr[n + 1];

  float acc[VE];
  {
    const float sw = dn * dn;
    if constexpr (VE == 4) {
      float4 v = reinterpret_cast<const float4*>(h + (size_t)n * F)[lane];
      acc[0] = v.x * sw; acc[1] = v.y * sw; acc[2] = v.z * sw; acc[3] = v.w * sw;
    } else {
      float2 v = reinterpret_cast<const float2*>(h + (size_t)n * F)[lane];
      acc[0] = v.x * sw; acc[1] = v.y * sw;
    }
  }
  for (int e = beg; e < end; ++e) {
    const int s = eidx[e];
    const float w = dinv[s] * dn;
    if constexpr (VE == 4) {
      float4 v = reinterpret_cast<const float4*>(h + (size_t)s * F)[lane];
      acc[0] = fmaf(v.x, w, acc[0]);
      acc[1] = fmaf(v.y, w, acc[1]);
      acc[2] = fmaf(v.z, w, acc[2]);
      acc[3] = fmaf(v.w, w, acc[3]);
    } else {
      float2 v = reinterpret_cast<const float2*>(h + (size_t)s * F)[lane];
      acc[0] = fmaf(v.x, w, acc[0]);
      acc[1] = fmaf(v.y, w, acc[1]);
    }
  }
  if constexpr (VE == 4) {
    float4 o; o.x = acc[0]; o.y = acc[1]; o.z = acc[2]; o.w = acc[3];
    reinterpret_cast<float4*>(out + (size_t)n * F)[lane] = o;
  } else {
    float2 o; o.x = acc[0]; o.y = acc[1];
    reinterpret_cast<float2*>(out + (size_t)n * F)[lane] = o;
  }
}

// ---------------- fused GEMM (+bias +LN +ReLU) ----------------
template<int K, int F, bool BIAS, bool LNORM, bool RELU>
__global__ __launch_bounds__(F) void k_gemm(
    const float* __restrict__ P, const float* __restrict__ W,
    const float* __restrict__ bias, const float* __restrict__ gamma,
    const float* __restrict__ beta, float* __restrict__ Out) {
  constexpr int R = 16;
  constexpr int NW = F / 64;
  const int f = threadIdx.x;
  const int row0 = blockIdx.x * R;

  float acc[R];
#pragma unroll
  for (int r = 0; r < R; ++r) acc[r] = 0.f;

  for (int kb = 0; kb < K; kb += 4) {
    const float w0 = W[(kb + 0) * F + f];
    const float w1 = W[(kb + 1) * F + f];
    const float w2 = W[(kb + 2) * F + f];
    const float w3 = W[(kb + 3) * F + f];
#pragma unroll
    for (int r = 0; r < R; ++r) {
      const float4 pv = *reinterpret_cast<const float4*>(&P[(size_t)(row0 + r) * K + kb]);
      acc[r] = fmaf(pv.w, w3, fmaf(pv.z, w2, fmaf(pv.y, w1, fmaf(pv.x, w0, acc[r]))));
    }
  }

  if constexpr (BIAS) {
    const float b = bias[f];
#pragma unroll
    for (int r = 0; r < R; ++r) acc[r] += b;
  }

  if constexpr (LNORM) {
    __shared__ float redS[NW][R];
    __shared__ float redQ[NW][R];
    const int wid = f >> 6, lane = f & 63;
#pragma unroll
    for (int r = 0; r < R; ++r) {
      float s = acc[r], q = acc[r] * acc[r];
#pragma unroll
      for (int off = 32; off > 0; off >>= 1) {
        s += __shfl_xor(s, off);
        q += __shfl_xor(q, off);
      }
      if (lane == 0) { redS[wid][r] = s; redQ[wid][r] = q; }
    }
    __syncthreads();
    const float gm = gamma[f], bt = beta[f];
#pragma unroll
    for (int r = 0; r < R; ++r) {
      float s = 0.f, q = 0.f;
#pragma unroll
      for (int w = 0; w < NW; ++w) { s += redS[w][r]; q += redQ[w][r]; }
      const float mean = s * (1.0f / F);
      const float var = q * (1.0f / F) - mean * mean;
      const float inv = rsqrtf(var + LN_EPS);
      float o = (acc[r] - mean) * inv * gm + bt;
      if constexpr (RELU) o = fmaxf(o, 0.f);
      Out[(size_t)(row0 + r) * F + f] = o;
    }
  } else {
#pragma unroll
    for (int r = 0; r < R; ++r) Out[(size_t)(row0 + r) * F + f] = acc[r];
  }
}

// ---------------- final bias + LN, in place on d_out (F=128) ----------------
__global__ void k_ln_final(float* __restrict__ io, const float* __restrict__ bias,
                           const float* __restrict__ g, const float* __restrict__ be) {
  const int row = blockIdx.x * 4 + (threadIdx.x >> 6);
  if (row >= NN) return;
  const int lane = threadIdx.x & 63;
  float2* rowp = reinterpret_cast<float2*>(io + (size_t)row * 128);
  float2 v = rowp[lane];
  const float2 bv = reinterpret_cast<const float2*>(bias)[lane];
  const float a0 = v.x + bv.x, a1 = v.y + bv.y;
  float s = a0 + a1, q = a0 * a0 + a1 * a1;
#pragma unroll
  for (int off = 32; off > 0; off >>= 1) {
    s += __shfl_xor(s, off);
    q += __shfl_xor(q, off);
  }
  const float mean = s * (1.0f / 128.0f);
  const float var = q * (1.0f / 128.0f) - mean * mean;
  const float inv = rsqrtf(var + LN_EPS);
  const float2 gv = reinterpret_cast<const float2*>(g)[lane];
  const float2 bev = reinterpret_cast<const float2*>(be)[lane];
  float2 o;
  o.x = (a0 - mean) * inv * gv.x + bev.x;
  o.y = (a1 - mean) * inv * gv.y + bev.y;
  rowp[lane] = o;
}

extern "C" void kernel_launch(void* const* d_in, const int* in_sizes, int n_in,
                              void* d_out, int out_size, void* d_ws, size_t ws_size,
                              hipStream_t stream) {
  const float* x   = (const float*)d_in[0];
  const int*   ei  = (const int*)d_in[1];
  const float* W1  = (const float*)d_in[2];
  const float* b1  = (const float*)d_in[3];
  const float* W2  = (const float*)d_in[4];
  const float* b2  = (const float*)d_in[5];
  const float* W3  = (const float*)d_in[6];
  const float* b3  = (const float*)d_in[7];
  const float* W4  = (const float*)d_in[8];
  const float* b4  = (const float*)d_in[9];
  const float* g1  = (const float*)d_in[10];
  const float* be1 = (const float*)d_in[11];
  const float* g2  = (const float*)d_in[12];
  const float* be2 = (const float*)d_in[13];
  const float* g3  = (const float*)d_in[14];
  const float* be3 = (const float*)d_in[15];
  const float* g4  = (const float*)d_in[16];
  const float* be4 = (const float*)d_in[17];

  const int* src = ei;          // edge_index[0]
  const int* dst = ei + NEDGE;  // edge_index[1]

  char* ws = (char*)d_ws;
  int*   cnt    = (int*)(ws + 0);              // NN ints
  int*   fill   = (int*)(ws + 204800);         // NN ints
  int*   rowptr = (int*)(ws + 409600);         // NN+1 ints
  float* dinv   = (float*)(ws + 614400);       // NN floats
  int*   eidx   = (int*)(ws + 819200);         // NEDGE ints
  float* bufA   = (float*)(ws + 2457600);      // NN*256 floats
  float* bufB   = bufA + (size_t)NN * 256;     // NN*256 floats
  float* out    = (float*)d_out;               // NN*128 floats

  // CSR build + dinv
  hipMemsetAsync(cnt, 0, 409600, stream);  // cnt + fill
  k_count<<<(NEDGE + 255) / 256, 256, 0, stream>>>(dst, cnt);
  k_dinv<<<(NN + 255) / 256, 256, 0, stream>>>(cnt, dinv);
  k_scan<<<1, 1024, 0, stream>>>(cnt, rowptr);
  k_fill<<<(NEDGE + 255) / 256, 256, 0, stream>>>(src, dst, rowptr, fill, eidx);

  // ---- Layer 1: aggregate x (F=128) -> GEMM 128->256 + LN + ReLU ----
  k_gather<128><<<(NN + 3) / 4, 256, 0, stream>>>(rowptr, eidx, dinv, x, bufA);
  k_gemm<128, 256, true, true, true><<<NN / 16, 256, 0, stream>>>(bufA, W1, b1, g1, be1, bufB);

  // ---- Layer 2 ----
  k_gather<256><<<(NN + 3) / 4, 256, 0, stream>>>(rowptr, eidx, dinv, bufB, bufA);
  k_gemm<256, 256, true, true, true><<<NN / 16, 256, 0, stream>>>(bufA, W2, b2, g2, be2, bufB);

  // ---- Layer 3 ----
  k_gather<256><<<(NN + 3) / 4, 256, 0, stream>>>(rowptr, eidx, dinv, bufB, bufA);
  k_gemm<256, 256, true, true, true><<<NN / 16, 256, 0, stream>>>(bufA, W3, b3, g3, be3, bufB);

  // ---- Layer 4: transform first (256->128), aggregate into d_out, bias+LN ----
  k_gemm<256, 128, false, false, false><<<NN / 16, 128, 0, stream>>>(bufB, W4, nullptr, nullptr, nullptr, bufA);
  k_gather<128><<<(NN + 3) / 4, 256, 0, stream>>>(rowptr, eidx, dinv, bufA, out);
  k_ln_final<<<(NN + 3) / 4, 256, 0, stream>>>(out, b4, g4, be4);
}

// Round 3
// 519.473 us; speedup vs baseline: 9.3776x; 2.2444x over previous
//
#include <hip/hip_runtime.h>

#define NN 50000
#define NEDGE 400000
#define MPAD 50048
constexpr float LN_EPS = 1e-5f;

typedef __attribute__((ext_vector_type(8))) short bf16x8;
typedef __attribute__((ext_vector_type(4))) float f32x4;

__device__ __forceinline__ unsigned short f2bf(float f) {  // RNE
  unsigned int u = __float_as_uint(f);
  u += 0x7FFFu + ((u >> 16) & 1u);
  return (unsigned short)(u >> 16);
}
__device__ __forceinline__ float bf2f(unsigned short u) {
  return __uint_as_float(((unsigned int)u) << 16);
}

// ---------------- CSR build ----------------
__global__ void k_count(const int* __restrict__ dst, int* __restrict__ cnt) {
  int e = blockIdx.x * blockDim.x + threadIdx.x;
  if (e < NEDGE) atomicAdd(&cnt[dst[e]], 1);
}

__global__ void k_dinv(const int* __restrict__ cnt, float* __restrict__ dinv) {
  int i = blockIdx.x * blockDim.x + threadIdx.x;
  if (i < NN) dinv[i] = rsqrtf((float)cnt[i] + 1.0f);
}

__global__ __launch_bounds__(1024) void k_scan(const int* __restrict__ cnt,
                                               int* __restrict__ rowptr) {
  constexpr int CH = (NN + 1023) / 1024;
  const int t = threadIdx.x;
  const int base = t * CH;
  int s = 0;
#pragma unroll
  for (int i = 0; i < CH; ++i) {
    int idx = base + i;
    if (idx < NN) s += cnt[idx];
  }
  const int lane = t & 63, wid = t >> 6;
  int inc = s;
  for (int off = 1; off < 64; off <<= 1) {
    int y = __shfl_up(inc, off);
    if (lane >= off) inc += y;
  }
  __shared__ int wsum[16];
  __shared__ int woff[16];
  if (lane == 63) wsum[wid] = inc;
  __syncthreads();
  if (t == 0) {
    int run = 0;
    for (int w = 0; w < 16; ++w) { woff[w] = run; run += wsum[w]; }
  }
  __syncthreads();
  int run = woff[wid] + inc - s;
  for (int i = 0; i < CH; ++i) {
    int idx = base + i;
    if (idx < NN) { rowptr[idx] = run; run += cnt[idx]; }
  }
  if (t == 1023) rowptr[NN] = run;
}

__global__ void k_fill(const int* __restrict__ src, const int* __restrict__ dst,
                       const int* __restrict__ rowptr, int* __restrict__ fill,
                       int* __restrict__ eidx) {
  int e = blockIdx.x * blockDim.x + threadIdx.x;
  if (e >= NEDGE) return;
  const int d = dst[e];
  const int p = rowptr[d] + atomicAdd(&fill[d], 1);
  eidx[p] = src[e];
}

// ---------------- weight transpose + bf16 convert: W[K][N] -> Wt[N][K] ----------------
__global__ void k_wconv(const float* __restrict__ W, unsigned short* __restrict__ Wt,
                        int K, int N) {
  const int k = blockIdx.x;
  const int n = threadIdx.x;
  Wt[(size_t)n * K + k] = f2bf(W[(size_t)k * N + n]);
}

// ---------------- gather aggregation (CSR), fp32 accum ----------------
template<int F, bool INBF, bool OUTBF>
__global__ __launch_bounds__(256) void k_gather(const int* __restrict__ rowptr,
                                                const int* __restrict__ eidx,
                                                const float* __restrict__ dinv,
                                                const void* __restrict__ hv,
                                                void* __restrict__ outv) {
  constexpr int VE = F / 64;  // floats per lane: 4 (F=256) or 2 (F=128)
  const int n = blockIdx.x * 4 + (threadIdx.x >> 6);
  if (n >= NN) return;
  const int lane = threadIdx.x & 63;
  const float dn = dinv[n];
  const int beg = rowptr[n], end = rowptr[n + 1];

  float acc[VE];
  const float sw = dn * dn;
#pragma unroll
  for (int i = 0; i < VE; ++i) acc[i] = 0.f;

  auto loadrow = [&](int r, float* v) {
    if constexpr (INBF) {
      const unsigned short* h = (const unsigned short*)hv;
      if constexpr (VE == 4) {
        ushort4 t = *reinterpret_cast<const ushort4*>(h + (size_t)r * F + lane * 4);
        v[0] = bf2f(t.x); v[1] = bf2f(t.y); v[2] = bf2f(t.z); v[3] = bf2f(t.w);
      } else {
        ushort2 t = *reinterpret_cast<const ushort2*>(h + (size_t)r * F + lane * 2);
        v[0] = bf2f(t.x); v[1] = bf2f(t.y);
      }
    } else {
      const float* h = (const float*)hv;
      if constexpr (VE == 4) {
        float4 t = *reinterpret_cast<const float4*>(h + (size_t)r * F + lane * 4);
        v[0] = t.x; v[1] = t.y; v[2] = t.z; v[3] = t.w;
      } else {
        float2 t = *reinterpret_cast<const float2*>(h + (size_t)r * F + lane * 2);
        v[0] = t.x; v[1] = t.y;
      }
    }
  };

  float v[VE];
  loadrow(n, v);
#pragma unroll
  for (int i = 0; i < VE; ++i) acc[i] = v[i] * sw;

  for (int e = beg; e < end; ++e) {
    const int s = eidx[e];
    const float w = dinv[s] * dn;
    loadrow(s, v);
#pragma unroll
    for (int i = 0; i < VE; ++i) acc[i] = fmaf(v[i], w, acc[i]);
  }

  if constexpr (OUTBF) {
    unsigned short* out = (unsigned short*)outv;
    if constexpr (VE == 4) {
      ushort4 o; o.x = f2bf(acc[0]); o.y = f2bf(acc[1]); o.z = f2bf(acc[2]); o.w = f2bf(acc[3]);
      *reinterpret_cast<ushort4*>(out + (size_t)n * F + lane * 4) = o;
    } else {
      ushort2 o; o.x = f2bf(acc[0]); o.y = f2bf(acc[1]);
      *reinterpret_cast<ushort2*>(out + (size_t)n * F + lane * 2) = o;
    }
  } else {
    float* out = (float*)outv;
    if constexpr (VE == 4) {
      float4 o; o.x = acc[0]; o.y = acc[1]; o.z = acc[2]; o.w = acc[3];
      *reinterpret_cast<float4*>(out + (size_t)n * F + lane * 4) = o;
    } else {
      float2 o; o.x = acc[0]; o.y = acc[1];
      *reinterpret_cast<float2*>(out + (size_t)n * F + lane * 2) = o;
    }
  }
}

// ---------------- MFMA GEMM: Out[M,N] = A[M,K](bf16) @ Bt[N,K](bf16)^T ----------------
// block: 4 waves, 64 rows; wave w owns cols [w*N/4, (w+1)*N/4)
template<int K, int N, bool OUTBF>
__global__ __launch_bounds__(256) void k_mgemm(const unsigned short* __restrict__ A,
                                               const unsigned short* __restrict__ Bt,
                                               void* __restrict__ outv) {
  constexpr int NT = N / 64;   // n-tiles (16 cols) per wave
  constexpr int KS = K / 32;   // k-steps
  __shared__ __align__(16) unsigned short As[64 * K];

  const int tid = threadIdx.x;
  const int lane = tid & 63;
  const int w = tid >> 6;
  const int m0 = blockIdx.x * 64;

  // stage A tile (rows m0..m0+63) into LDS with XOR swizzle on 16B slots
#pragma unroll
  for (int i = 0; i < KS; ++i) {
    const int o = (i * 256 + tid) * 16;          // linear byte offset in tile
    const int row = o / (2 * K);
    const int inb = o % (2 * K);
    uint4 val = *reinterpret_cast<const uint4*>(
        (const char*)A + (size_t)(m0 + row) * (2 * K) + inb);
    const int dsto = o ^ ((row & 7) << 4);
    *reinterpret_cast<uint4*>((char*)As + dsto) = val;
  }
  __syncthreads();

  f32x4 acc[4][NT];
#pragma unroll
  for (int mt = 0; mt < 4; ++mt)
#pragma unroll
    for (int nt = 0; nt < NT; ++nt) acc[mt][nt] = (f32x4){0.f, 0.f, 0.f, 0.f};

  const int nw0 = w * (N / 4);
  const int arow = lane & 15;
  const int kgrp = (lane >> 4) * 8;

  for (int ks = 0; ks < KS; ++ks) {
    bf16x8 af[4];
#pragma unroll
    for (int mt = 0; mt < 4; ++mt) {
      const int r = mt * 16 + arow;
      int boff = (r * K + ks * 32 + kgrp) * 2;
      boff ^= (r & 7) << 4;
      af[mt] = *reinterpret_cast<const bf16x8*>((const char*)As + boff);
    }
    bf16x8 bfr[NT];
#pragma unroll
    for (int nt = 0; nt < NT; ++nt) {
      const int n = nw0 + nt * 16 + arow;
      bfr[nt] = *reinterpret_cast<const bf16x8*>(Bt + (size_t)n * K + ks * 32 + kgrp);
    }
#pragma unroll
    for (int mt = 0; mt < 4; ++mt)
#pragma unroll
      for (int nt = 0; nt < NT; ++nt)
        acc[mt][nt] = __builtin_amdgcn_mfma_f32_16x16x32_bf16(af[mt], bfr[nt], acc[mt][nt], 0, 0, 0);
  }

  const int rbase = (lane >> 4) * 4;
#pragma unroll
  for (int mt = 0; mt < 4; ++mt) {
#pragma unroll
    for (int nt = 0; nt < NT; ++nt) {
      const int c = nw0 + nt * 16 + (lane & 15);
#pragma unroll
      for (int reg = 0; reg < 4; ++reg) {
        const int r = m0 + mt * 16 + rbase + reg;
        if (r < NN) {
          if constexpr (OUTBF)
            ((unsigned short*)outv)[(size_t)r * N + c] = f2bf(acc[mt][nt][reg]);
          else
            ((float*)outv)[(size_t)r * N + c] = acc[mt][nt][reg];
        }
      }
    }
  }
}

// ---------------- bias + LN + ReLU, fp32 in -> bf16 out (N=256) ----------------
__global__ __launch_bounds__(256) void k_lnrelu(const float* __restrict__ in,
                                                const float* __restrict__ bias,
                                                const float* __restrict__ g,
                                                const float* __restrict__ be,
                                                unsigned short* __restrict__ out) {
  const int row = blockIdx.x * 4 + (threadIdx.x >> 6);
  if (row >= NN) return;
  const int lane = threadIdx.x & 63;
  float4 a = *reinterpret_cast<const float4*>(in + (size_t)row * 256 + lane * 4);
  const float4 bv = reinterpret_cast<const float4*>(bias)[lane];
  a.x += bv.x; a.y += bv.y; a.z += bv.z; a.w += bv.w;
  float s = a.x + a.y + a.z + a.w;
  float q = a.x * a.x + a.y * a.y + a.z * a.z + a.w * a.w;
#pragma unroll
  for (int off = 32; off > 0; off >>= 1) {
    s += __shfl_xor(s, off);
    q += __shfl_xor(q, off);
  }
  const float mean = s * (1.0f / 256.0f);
  const float var = q * (1.0f / 256.0f) - mean * mean;
  const float inv = rsqrtf(var + LN_EPS);
  const float4 gv = reinterpret_cast<const float4*>(g)[lane];
  const float4 bev = reinterpret_cast<const float4*>(be)[lane];
  float o0 = fmaxf((a.x - mean) * inv * gv.x + bev.x, 0.f);
  float o1 = fmaxf((a.y - mean) * inv * gv.y + bev.y, 0.f);
  float o2 = fmaxf((a.z - mean) * inv * gv.z + bev.z, 0.f);
  float o3 = fmaxf((a.w - mean) * inv * gv.w + bev.w, 0.f);
  ushort4 o; o.x = f2bf(o0); o.y = f2bf(o1); o.z = f2bf(o2); o.w = f2bf(o3);
  *reinterpret_cast<ushort4*>(out + (size_t)row * 256 + lane * 4) = o;
}

// ---------------- final bias + LN, in place on d_out (F=128, fp32) ----------------
__global__ void k_ln_final(float* __restrict__ io, const float* __restrict__ bias,
                           const float* __restrict__ g, const float* __restrict__ be) {
  const int row = blockIdx.x * 4 + (threadIdx.x >> 6);
  if (row >= NN) return;
  const int lane = threadIdx.x & 63;
  float2* rowp = reinterpret_cast<float2*>(io + (size_t)row * 128);
  float2 v = rowp[lane];
  const float2 bv = reinterpret_cast<const float2*>(bias)[lane];
  const float a0 = v.x + bv.x, a1 = v.y + bv.y;
  float s = a0 + a1, q = a0 * a0 + a1 * a1;
#pragma unroll
  for (int off = 32; off > 0; off >>= 1) {
    s += __shfl_xor(s, off);
    q += __shfl_xor(q, off);
  }
  const float mean = s * (1.0f / 128.0f);
  const float var = q * (1.0f / 128.0f) - mean * mean;
  const float inv = rsqrtf(var + LN_EPS);
  const float2 gv = reinterpret_cast<const float2*>(g)[lane];
  const float2 bev = reinterpret_cast<const float2*>(be)[lane];
  float2 o;
  o.x = (a0 - mean) * inv * gv.x + bev.x;
  o.y = (a1 - mean) * inv * gv.y + bev.y;
  rowp[lane] = o;
}

extern "C" void kernel_launch(void* const* d_in, const int* in_sizes, int n_in,
                              void* d_out, int out_size, void* d_ws, size_t ws_size,
                              hipStream_t stream) {
  const float* x   = (const float*)d_in[0];
  const int*   ei  = (const int*)d_in[1];
  const float* W1  = (const float*)d_in[2];
  const float* b1  = (const float*)d_in[3];
  const float* W2  = (const float*)d_in[4];
  const float* b2  = (const float*)d_in[5];
  const float* W3  = (const float*)d_in[6];
  const float* b3  = (const float*)d_in[7];
  const float* W4  = (const float*)d_in[8];
  const float* b4  = (const float*)d_in[9];
  const float* g1  = (const float*)d_in[10];
  const float* be1 = (const float*)d_in[11];
  const float* g2  = (const float*)d_in[12];
  const float* be2 = (const float*)d_in[13];
  const float* g3  = (const float*)d_in[14];
  const float* be3 = (const float*)d_in[15];
  const float* g4  = (const float*)d_in[16];
  const float* be4 = (const float*)d_in[17];

  const int* src = ei;
  const int* dst = ei + NEDGE;

  char* ws = (char*)d_ws;
  int*   cnt    = (int*)(ws + 0);              // NN ints
  int*   fill   = (int*)(ws + 204800);         // NN ints
  int*   rowptr = (int*)(ws + 409600);         // NN+1 ints
  float* dinv   = (float*)(ws + 614400);       // NN floats
  int*   eidx   = (int*)(ws + 819200);         // NEDGE ints
  unsigned short* Wt1 = (unsigned short*)(ws + 2457600);   // 256x128
  unsigned short* Wt2 = (unsigned short*)(ws + 2523136);   // 256x256
  unsigned short* Wt3 = (unsigned short*)(ws + 2654208);   // 256x256
  unsigned short* Wt4 = (unsigned short*)(ws + 2785280);   // 128x256
  unsigned short* aggB = (unsigned short*)(ws + 2850816);  // MPAD x 256 bf16
  unsigned short* hB   = (unsigned short*)(ws + 28475392); // MPAD x 256 bf16
  float* gemmO = (float*)(ws + 54099968);                  // MPAD x 256 f32
  unsigned short* t4B = (unsigned short*)gemmO;            // alias: MPAD x 128 bf16
  float* out = (float*)d_out;

  const int MB = (NN + 63) / 64;  // 782

  // CSR + dinv + weight conversion
  hipMemsetAsync(cnt, 0, 409600, stream);
  k_count<<<(NEDGE + 255) / 256, 256, 0, stream>>>(dst, cnt);
  k_dinv<<<(NN + 255) / 256, 256, 0, stream>>>(cnt, dinv);
  k_scan<<<1, 1024, 0, stream>>>(cnt, rowptr);
  k_fill<<<(NEDGE + 255) / 256, 256, 0, stream>>>(src, dst, rowptr, fill, eidx);
  k_wconv<<<128, 256, 0, stream>>>(W1, Wt1, 128, 256);
  k_wconv<<<256, 256, 0, stream>>>(W2, Wt2, 256, 256);
  k_wconv<<<256, 256, 0, stream>>>(W3, Wt3, 256, 256);
  k_wconv<<<256, 128, 0, stream>>>(W4, Wt4, 256, 128);

  // ---- Layer 1 ----
  k_gather<128, false, true><<<(NN + 3) / 4, 256, 0, stream>>>(rowptr, eidx, dinv, x, aggB);
  k_mgemm<128, 256, false><<<MB, 256, 0, stream>>>(aggB, Wt1, gemmO);
  k_lnrelu<<<(NN + 3) / 4, 256, 0, stream>>>(gemmO, b1, g1, be1, hB);

  // ---- Layer 2 ----
  k_gather<256, true, true><<<(NN + 3) / 4, 256, 0, stream>>>(rowptr, eidx, dinv, hB, aggB);
  k_mgemm<256, 256, false><<<MB, 256, 0, stream>>>(aggB, Wt2, gemmO);
  k_lnrelu<<<(NN + 3) / 4, 256, 0, stream>>>(gemmO, b2, g2, be2, hB);

  // ---- Layer 3 ----
  k_gather<256, true, true><<<(NN + 3) / 4, 256, 0, stream>>>(rowptr, eidx, dinv, hB, aggB);
  k_mgemm<256, 256, false><<<MB, 256, 0, stream>>>(aggB, Wt3, gemmO);
  k_lnrelu<<<(NN + 3) / 4, 256, 0, stream>>>(gemmO, b3, g3, be3, hB);

  // ---- Layer 4: transform (256->128) -> gather into d_out -> bias+LN ----
  k_mgemm<256, 128, true><<<MB, 256, 0, stream>>>(hB, Wt4, t4B);
  k_gather<128, true, false><<<(NN + 3) / 4, 256, 0, stream>>>(rowptr, eidx, dinv, t4B, out);
  k_ln_final<<<(NN + 3) / 4, 256, 0, stream>>>(out, b4, g4, be4);
}

// Round 4
// 335.552 us; speedup vs baseline: 14.5176x; 1.5481x over previous
//
#include <hip/hip_runtime.h>

#define NN 50000
#define NEDGE 400000
#define MPAD 50048
#define NB 196  // scan blocks: 196*256 = 50176 >= NN
constexpr float LN_EPS = 1e-5f;

typedef __attribute__((ext_vector_type(8))) short bf16x8;
typedef __attribute__((ext_vector_type(4))) float f32x4;

__device__ __forceinline__ unsigned short f2bf(float f) {  // RNE
  unsigned int u = __float_as_uint(f);
  u += 0x7FFFu + ((u >> 16) & 1u);
  return (unsigned short)(u >> 16);
}
__device__ __forceinline__ float bf2f(unsigned short u) {
  return __uint_as_float(((unsigned int)u) << 16);
}

// ---------------- CSR build ----------------
__global__ void k_count(const int* __restrict__ dst, int* __restrict__ cnt) {
  int e = blockIdx.x * blockDim.x + threadIdx.x;
  if (e < NEDGE) atomicAdd(&cnt[dst[e]], 1);
}

// block partial sums of cnt (+ fused dinv)
__global__ __launch_bounds__(256) void k_bsum(const int* __restrict__ cnt,
                                              int* __restrict__ bsum,
                                              float* __restrict__ dinv) {
  const int i = blockIdx.x * 256 + threadIdx.x;
  int v = 0;
  if (i < NN) {
    v = cnt[i];
    dinv[i] = rsqrtf((float)v + 1.0f);
  }
  int s = v;
#pragma unroll
  for (int off = 32; off > 0; off >>= 1) s += __shfl_xor(s, off);
  __shared__ int wsum[4];
  if ((threadIdx.x & 63) == 0) wsum[threadIdx.x >> 6] = s;
  __syncthreads();
  if (threadIdx.x == 0) bsum[blockIdx.x] = wsum[0] + wsum[1] + wsum[2] + wsum[3];
}

// exclusive scan of the NB block sums
__global__ __launch_bounds__(256) void k_bscan(const int* __restrict__ bsum,
                                               int* __restrict__ boff,
                                               int* __restrict__ rowptr) {
  const int t = threadIdx.x;
  const int lane = t & 63, wid = t >> 6;
  int v = (t < NB) ? bsum[t] : 0;
  int inc = v;
  for (int off = 1; off < 64; off <<= 1) {
    int y = __shfl_up(inc, off);
    if (lane >= off) inc += y;
  }
  __shared__ int wsum[4], woff[4];
  if (lane == 63) wsum[wid] = inc;
  __syncthreads();
  if (t == 0) {
    int run = 0;
    for (int w = 0; w < 4; ++w) { woff[w] = run; run += wsum[w]; }
    rowptr[NN] = NEDGE;
  }
  __syncthreads();
  if (t < NB) boff[t] = woff[wid] + inc - v;
}

// per-block exclusive scan + block offset -> rowptr
__global__ __launch_bounds__(256) void k_bapply(const int* __restrict__ cnt,
                                                const int* __restrict__ boff,
                                                int* __restrict__ rowptr) {
  const int t = threadIdx.x;
  const int i = blockIdx.x * 256 + t;
  const int lane = t & 63, wid = t >> 6;
  int v = (i < NN) ? cnt[i] : 0;
  int inc = v;
  for (int off = 1; off < 64; off <<= 1) {
    int y = __shfl_up(inc, off);
    if (lane >= off) inc += y;
  }
  __shared__ int wsum[4], woff[4];
  if (lane == 63) wsum[wid] = inc;
  __syncthreads();
  if (t == 0) {
    int run = 0;
    for (int w = 0; w < 4; ++w) { woff[w] = run; run += wsum[w]; }
  }
  __syncthreads();
  if (i < NN) rowptr[i] = boff[blockIdx.x] + woff[wid] + inc - v;
}

__global__ void k_fill(const int* __restrict__ src, const int* __restrict__ dst,
                       const int* __restrict__ rowptr, int* __restrict__ fill,
                       int* __restrict__ eidx) {
  int e = blockIdx.x * blockDim.x + threadIdx.x;
  if (e >= NEDGE) return;
  const int d = dst[e];
  const int p = rowptr[d] + atomicAdd(&fill[d], 1);
  eidx[p] = src[e];
}

// ---------------- all 4 weights: transpose + bf16 in one launch ----------------
__global__ __launch_bounds__(256) void k_wconv_all(
    const float* __restrict__ W1, const float* __restrict__ W2,
    const float* __restrict__ W3, const float* __restrict__ W4,
    unsigned short* __restrict__ Wt1, unsigned short* __restrict__ Wt2,
    unsigned short* __restrict__ Wt3, unsigned short* __restrict__ Wt4) {
  const int b = blockIdx.x;
  const int n = threadIdx.x;
  if (b < 128) {                       // W1: K=128,N=256
    Wt1[(size_t)n * 128 + b] = f2bf(W1[(size_t)b * 256 + n]);
  } else if (b < 384) {                // W2: K=256,N=256
    const int k = b - 128;
    Wt2[(size_t)n * 256 + k] = f2bf(W2[(size_t)k * 256 + n]);
  } else if (b < 640) {                // W3
    const int k = b - 384;
    Wt3[(size_t)n * 256 + k] = f2bf(W3[(size_t)k * 256 + n]);
  } else {                             // W4: K=256,N=128
    const int k = b - 640;
    if (n < 128) Wt4[(size_t)n * 256 + k] = f2bf(W4[(size_t)k * 128 + n]);
  }
}

// ---------------- x -> bf16 ----------------
__global__ void k_xconv(const float* __restrict__ in, unsigned short* __restrict__ out) {
  const int i = blockIdx.x * blockDim.x + threadIdx.x;  // one float4 per thread
  if (i >= NN * 32) return;
  float4 v = reinterpret_cast<const float4*>(in)[i];
  ushort4 o; o.x = f2bf(v.x); o.y = f2bf(v.y); o.z = f2bf(v.z); o.w = f2bf(v.w);
  reinterpret_cast<ushort4*>(out)[i] = o;
}

// ---------------- gather aggregation (CSR), fp32 accum, bf16 rows ----------------
template<int F, bool OUTBF>
__global__ __launch_bounds__(256) void k_gather(const int* __restrict__ rowptr,
                                                const int* __restrict__ eidx,
                                                const float* __restrict__ dinv,
                                                const unsigned short* __restrict__ h,
                                                void* __restrict__ outv) {
  constexpr int VE = F / 64;  // elems per lane: 4 (F=256) or 2 (F=128)
  const int n = blockIdx.x * 4 + (threadIdx.x >> 6);
  if (n >= NN) return;
  const int lane = threadIdx.x & 63;
  const float dn = dinv[n];
  const int beg = rowptr[n], end = rowptr[n + 1];

  float acc[VE];

  auto loadrow = [&](int r, float* v) {
    if constexpr (VE == 4) {
      ushort4 t = *reinterpret_cast<const ushort4*>(h + (size_t)r * F + lane * 4);
      v[0] = bf2f(t.x); v[1] = bf2f(t.y); v[2] = bf2f(t.z); v[3] = bf2f(t.w);
    } else {
      ushort2 t = *reinterpret_cast<const ushort2*>(h + (size_t)r * F + lane * 2);
      v[0] = bf2f(t.x); v[1] = bf2f(t.y);
    }
  };

  float v0[VE], v1[VE];
  loadrow(n, v0);
  const float sw = dn * dn;
#pragma unroll
  for (int i = 0; i < VE; ++i) acc[i] = v0[i] * sw;

  int e = beg;
  for (; e + 1 < end; e += 2) {
    const int s0 = eidx[e], s1 = eidx[e + 1];
    const float w0 = dinv[s0] * dn;
    const float w1 = dinv[s1] * dn;
    loadrow(s0, v0);
    loadrow(s1, v1);
#pragma unroll
    for (int i = 0; i < VE; ++i) {
      acc[i] = fmaf(v0[i], w0, acc[i]);
      acc[i] = fmaf(v1[i], w1, acc[i]);
    }
  }
  if (e < end) {
    const int s0 = eidx[e];
    const float w0 = dinv[s0] * dn;
    loadrow(s0, v0);
#pragma unroll
    for (int i = 0; i < VE; ++i) acc[i] = fmaf(v0[i], w0, acc[i]);
  }

  if constexpr (OUTBF) {
    unsigned short* out = (unsigned short*)outv;
    if constexpr (VE == 4) {
      ushort4 o; o.x = f2bf(acc[0]); o.y = f2bf(acc[1]); o.z = f2bf(acc[2]); o.w = f2bf(acc[3]);
      *reinterpret_cast<ushort4*>(out + (size_t)n * F + lane * 4) = o;
    } else {
      ushort2 o; o.x = f2bf(acc[0]); o.y = f2bf(acc[1]);
      *reinterpret_cast<ushort2*>(out + (size_t)n * F + lane * 2) = o;
    }
  } else {
    float* out = (float*)outv;
    if constexpr (VE == 4) {
      float4 o; o.x = acc[0]; o.y = acc[1]; o.z = acc[2]; o.w = acc[3];
      *reinterpret_cast<float4*>(out + (size_t)n * F + lane * 4) = o;
    } else {
      float2 o; o.x = acc[0]; o.y = acc[1];
      *reinterpret_cast<float2*>(out + (size_t)n * F + lane * 2) = o;
    }
  }
}

// ---------------- MFMA GEMM, optional fused bias+LN+ReLU epilogue ----------------
// block: 4 waves, 64 rows; wave w owns cols [w*N/4, (w+1)*N/4)
template<int K, int N, bool LNFUSE>
__global__ __launch_bounds__(256) void k_mgemm(const unsigned short* __restrict__ A,
                                               const unsigned short* __restrict__ Bt,
                                               const float* __restrict__ bias,
                                               const float* __restrict__ gamma,
                                               const float* __restrict__ beta,
                                               unsigned short* __restrict__ out) {
  constexpr int NT = N / 64;   // 16-col tiles per wave
  constexpr int KS = K / 32;   // k-steps
  __shared__ __align__(16) unsigned short As[64 * K];

  const int tid = threadIdx.x;
  const int lane = tid & 63;
  const int w = tid >> 6;
  const int m0 = blockIdx.x * 64;

  // stage A tile into LDS with XOR swizzle on 16B slots
#pragma unroll
  for (int i = 0; i < KS; ++i) {
    const int o = (i * 256 + tid) * 16;
    const int row = o / (2 * K);
    const int inb = o % (2 * K);
    uint4 val = *reinterpret_cast<const uint4*>(
        (const char*)A + (size_t)(m0 + row) * (2 * K) + inb);
    const int dsto = o ^ ((row & 7) << 4);
    *reinterpret_cast<uint4*>((char*)As + dsto) = val;
  }
  __syncthreads();

  f32x4 acc[4][NT];
#pragma unroll
  for (int mt = 0; mt < 4; ++mt)
#pragma unroll
    for (int nt = 0; nt < NT; ++nt) acc[mt][nt] = (f32x4){0.f, 0.f, 0.f, 0.f};

  const int nw0 = w * (N / 4);
  const int arow = lane & 15;
  const int kgrp = (lane >> 4) * 8;

  for (int ks = 0; ks < KS; ++ks) {
    bf16x8 af[4];
#pragma unroll
    for (int mt = 0; mt < 4; ++mt) {
      const int r = mt * 16 + arow;
      int boff = (r * K + ks * 32 + kgrp) * 2;
      boff ^= (r & 7) << 4;
      af[mt] = *reinterpret_cast<const bf16x8*>((const char*)As + boff);
    }
    bf16x8 bfr[NT];
#pragma unroll
    for (int nt = 0; nt < NT; ++nt) {
      const int n = nw0 + nt * 16 + arow;
      bfr[nt] = *reinterpret_cast<const bf16x8*>(Bt + (size_t)n * K + ks * 32 + kgrp);
    }
#pragma unroll
    for (int mt = 0; mt < 4; ++mt)
#pragma unroll
      for (int nt = 0; nt < NT; ++nt)
        acc[mt][nt] = __builtin_amdgcn_mfma_f32_16x16x32_bf16(af[mt], bfr[nt], acc[mt][nt], 0, 0, 0);
  }

  const int g = lane >> 4;       // 16-lane group: rows g*4..g*4+3 (+16*mt)
  const int cl = lane & 15;      // col within 16-tile

  if constexpr (LNFUSE) {
    // bias add (per column)
    float gv[NT], bev[NT];
#pragma unroll
    for (int nt = 0; nt < NT; ++nt) {
      const int c = nw0 + nt * 16 + cl;
      const float bv = bias[c];
      gv[nt] = gamma[c];
      bev[nt] = beta[c];
#pragma unroll
      for (int mt = 0; mt < 4; ++mt)
#pragma unroll
        for (int reg = 0; reg < 4; ++reg) acc[mt][nt][reg] += bv;
    }
    // per-row partial sums over this wave's 64 cols
    __shared__ float sS[4][64];
    __shared__ float sQ[4][64];
    float ps[4][4], pq[4][4];
#pragma unroll
    for (int mt = 0; mt < 4; ++mt) {
#pragma unroll
      for (int reg = 0; reg < 4; ++reg) {
        float s = 0.f, q = 0.f;
#pragma unroll
        for (int nt = 0; nt < NT; ++nt) {
          const float v = acc[mt][nt][reg];
          s += v; q = fmaf(v, v, q);
        }
#pragma unroll
        for (int off = 1; off < 16; off <<= 1) {
          s += __shfl_xor(s, off);
          q += __shfl_xor(q, off);
        }
        ps[mt][reg] = s; pq[mt][reg] = q;
      }
    }
    if (cl == 0) {
#pragma unroll
      for (int mt = 0; mt < 4; ++mt)
#pragma unroll
        for (int reg = 0; reg < 4; ++reg) {
          sS[w][mt * 16 + g * 4 + reg] = ps[mt][reg];
          sQ[w][mt * 16 + g * 4 + reg] = pq[mt][reg];
        }
    }
    __syncthreads();
#pragma unroll
    for (int mt = 0; mt < 4; ++mt) {
#pragma unroll
      for (int reg = 0; reg < 4; ++reg) {
        const int rr = mt * 16 + g * 4 + reg;
        const int r = m0 + rr;
        const float S = sS[0][rr] + sS[1][rr] + sS[2][rr] + sS[3][rr];
        const float Q = sQ[0][rr] + sQ[1][rr] + sQ[2][rr] + sQ[3][rr];
        const float mean = S * (1.0f / N);
        const float var = Q * (1.0f / N) - mean * mean;
        const float inv = rsqrtf(var + LN_EPS);
        if (r < NN) {
#pragma unroll
          for (int nt = 0; nt < NT; ++nt) {
            const int c = nw0 + nt * 16 + cl;
            const float o = fmaxf((acc[mt][nt][reg] - mean) * inv * gv[nt] + bev[nt], 0.f);
            out[(size_t)r * N + c] = f2bf(o);
          }
        }
      }
    }
  } else {
#pragma unroll
    for (int mt = 0; mt < 4; ++mt) {
#pragma unroll
      for (int nt = 0; nt < NT; ++nt) {
        const int c = nw0 + nt * 16 + cl;
#pragma unroll
        for (int reg = 0; reg < 4; ++reg) {
          const int r = m0 + mt * 16 + g * 4 + reg;
          if (r < NN) out[(size_t)r * N + c] = f2bf(acc[mt][nt][reg]);
        }
      }
    }
  }
}

// ---------------- final bias + LN, in place on d_out (F=128, fp32) ----------------
__global__ void k_ln_final(float* __restrict__ io, const float* __restrict__ bias,
                           const float* __restrict__ g, const float* __restrict__ be) {
  const int row = blockIdx.x * 4 + (threadIdx.x >> 6);
  if (row >= NN) return;
  const int lane = threadIdx.x & 63;
  float2* rowp = reinterpret_cast<float2*>(io + (size_t)row * 128);
  float2 v = rowp[lane];
  const float2 bv = reinterpret_cast<const float2*>(bias)[lane];
  const float a0 = v.x + bv.x, a1 = v.y + bv.y;
  float s = a0 + a1, q = a0 * a0 + a1 * a1;
#pragma unroll
  for (int off = 32; off > 0; off >>= 1) {
    s += __shfl_xor(s, off);
    q += __shfl_xor(q, off);
  }
  const float mean = s * (1.0f / 128.0f);
  const float var = q * (1.0f / 128.0f) - mean * mean;
  const float inv = rsqrtf(var + LN_EPS);
  const float2 gv = reinterpret_cast<const float2*>(g)[lane];
  const float2 bev = reinterpret_cast<const float2*>(be)[lane];
  float2 o;
  o.x = (a0 - mean) * inv * gv.x + bev.x;
  o.y = (a1 - mean) * inv * gv.y + bev.y;
  rowp[lane] = o;
}

extern "C" void kernel_launch(void* const* d_in, const int* in_sizes, int n_in,
                              void* d_out, int out_size, void* d_ws, size_t ws_size,
                              hipStream_t stream) {
  const float* x   = (const float*)d_in[0];
  const int*   ei  = (const int*)d_in[1];
  const float* W1  = (const float*)d_in[2];
  const float* b1  = (const float*)d_in[3];
  const float* W2  = (const float*)d_in[4];
  const float* b2  = (const float*)d_in[5];
  const float* W3  = (const float*)d_in[6];
  const float* b3  = (const float*)d_in[7];
  const float* W4  = (const float*)d_in[8];
  const float* b4  = (const float*)d_in[9];
  const float* g1  = (const float*)d_in[10];
  const float* be1 = (const float*)d_in[11];
  const float* g2  = (const float*)d_in[12];
  const float* be2 = (const float*)d_in[13];
  const float* g3  = (const float*)d_in[14];
  const float* be3 = (const float*)d_in[15];
  const float* g4  = (const float*)d_in[16];
  const float* be4 = (const float*)d_in[17];

  const int* src = ei;
  const int* dst = ei + NEDGE;

  char* ws = (char*)d_ws;
  int*   cnt    = (int*)(ws + 0);              // NN ints (reserve 204800)
  int*   fill   = (int*)(ws + 204800);         // NN ints
  int*   rowptr = (int*)(ws + 409600);         // NN+1 ints
  float* dinv   = (float*)(ws + 614400);       // NN floats
  int*   bsum   = (int*)(ws + 819200);         // NB ints
  int*   boff   = (int*)(ws + 823296);         // NB ints
  int*   eidx   = (int*)(ws + 827392);         // NEDGE ints (1.6MB)
  unsigned short* Wt1 = (unsigned short*)(ws + 2465792);   // 256x128
  unsigned short* Wt2 = (unsigned short*)(ws + 2531328);   // 256x256
  unsigned short* Wt3 = (unsigned short*)(ws + 2662400);   // 256x256
  unsigned short* Wt4 = (unsigned short*)(ws + 2793472);   // 128x256
  unsigned short* xB  = (unsigned short*)(ws + 2859008);   // MPAD x 128 bf16
  unsigned short* aggB = (unsigned short*)(ws + 15671296); // MPAD x 256 bf16
  unsigned short* hB   = (unsigned short*)(ws + 41295872); // MPAD x 256 bf16
  unsigned short* t4B  = (unsigned short*)(ws + 66920448); // MPAD x 128 bf16
  float* out = (float*)d_out;

  const int MB = (NN + 63) / 64;  // 782

  // CSR + dinv + weight/x conversion
  hipMemsetAsync(cnt, 0, 409600, stream);  // cnt + fill
  k_count<<<(NEDGE + 255) / 256, 256, 0, stream>>>(dst, cnt);
  k_bsum<<<NB, 256, 0, stream>>>(cnt, bsum, dinv);
  k_bscan<<<1, 256, 0, stream>>>(bsum, boff, rowptr);
  k_bapply<<<NB, 256, 0, stream>>>(cnt, boff, rowptr);
  k_fill<<<(NEDGE + 255) / 256, 256, 0, stream>>>(src, dst, rowptr, fill, eidx);
  k_wconv_all<<<896, 256, 0, stream>>>(W1, W2, W3, W4, Wt1, Wt2, Wt3, Wt4);
  k_xconv<<<(NN * 32 + 255) / 256, 256, 0, stream>>>(x, xB);

  // ---- Layer 1 ----
  k_gather<128, true><<<(NN + 3) / 4, 256, 0, stream>>>(rowptr, eidx, dinv, xB, aggB);
  k_mgemm<128, 256, true><<<MB, 256, 0, stream>>>(aggB, Wt1, b1, g1, be1, hB);

  // ---- Layer 2 ----
  k_gather<256, true><<<(NN + 3) / 4, 256, 0, stream>>>(rowptr, eidx, dinv, hB, aggB);
  k_mgemm<256, 256, true><<<MB, 256, 0, stream>>>(aggB, Wt2, b2, g2, be2, hB);

  // ---- Layer 3 ----
  k_gather<256, true><<<(NN + 3) / 4, 256, 0, stream>>>(rowptr, eidx, dinv, hB, aggB);
  k_mgemm<256, 256, true><<<MB, 256, 0, stream>>>(aggB, Wt3, b3, g3, be3, hB);

  // ---- Layer 4: transform (256->128) -> gather into d_out -> bias+LN ----
  k_mgemm<256, 128, false><<<MB, 256, 0, stream>>>(hB, Wt4, nullptr, nullptr, nullptr, t4B);
  k_gather<128, false><<<(NN + 3) / 4, 256, 0, stream>>>(rowptr, eidx, dinv, t4B, out);
  k_ln_final<<<(NN + 3) / 4, 256, 0, stream>>>(out, b4, g4, be4);
}

// Round 5
// 297.840 us; speedup vs baseline: 16.3558x; 1.1266x over previous
//
#include <hip/hip_runtime.h>

#define NN 50000
#define NEDGE 400000
#define MPAD 50048
#define NB 196  // scan blocks: 196*256 = 50176 >= NN
constexpr float LN_EPS = 1e-5f;

typedef __attribute__((ext_vector_type(8))) short bf16x8;
typedef __attribute__((ext_vector_type(4))) float f32x4;
typedef __attribute__((ext_vector_type(8))) unsigned short ushort8v;

__device__ __forceinline__ unsigned short f2bf(float f) {  // RNE
  unsigned int u = __float_as_uint(f);
  u += 0x7FFFu + ((u >> 16) & 1u);
  return (unsigned short)(u >> 16);
}
__device__ __forceinline__ float bf2f(unsigned short u) {
  return __uint_as_float(((unsigned int)u) << 16);
}

// ---------------- CSR build ----------------
__global__ void k_count(const int* __restrict__ dst, int* __restrict__ cnt) {
  int e = blockIdx.x * blockDim.x + threadIdx.x;
  if (e < NEDGE) atomicAdd(&cnt[dst[e]], 1);
}

// block partial sums of cnt (+ fused dinv)
__global__ __launch_bounds__(256) void k_bsum(const int* __restrict__ cnt,
                                              int* __restrict__ bsum,
                                              float* __restrict__ dinv) {
  const int i = blockIdx.x * 256 + threadIdx.x;
  int v = 0;
  if (i < NN) {
    v = cnt[i];
    dinv[i] = rsqrtf((float)v + 1.0f);
  }
  int s = v;
#pragma unroll
  for (int off = 32; off > 0; off >>= 1) s += __shfl_xor(s, off);
  __shared__ int wsum[4];
  if ((threadIdx.x & 63) == 0) wsum[threadIdx.x >> 6] = s;
  __syncthreads();
  if (threadIdx.x == 0) bsum[blockIdx.x] = wsum[0] + wsum[1] + wsum[2] + wsum[3];
}

// exclusive scan of the NB block sums
__global__ __launch_bounds__(256) void k_bscan(const int* __restrict__ bsum,
                                               int* __restrict__ boff,
                                               int* __restrict__ rowptr) {
  const int t = threadIdx.x;
  const int lane = t & 63, wid = t >> 6;
  int v = (t < NB) ? bsum[t] : 0;
  int inc = v;
  for (int off = 1; off < 64; off <<= 1) {
    int y = __shfl_up(inc, off);
    if (lane >= off) inc += y;
  }
  __shared__ int wsum[4], woff[4];
  if (lane == 63) wsum[wid] = inc;
  __syncthreads();
  if (t == 0) {
    int run = 0;
    for (int w = 0; w < 4; ++w) { woff[w] = run; run += wsum[w]; }
    rowptr[NN] = NEDGE;
  }
  __syncthreads();
  if (t < NB) boff[t] = woff[wid] + inc - v;
}

// per-block exclusive scan + block offset -> rowptr
__global__ __launch_bounds__(256) void k_bapply(const int* __restrict__ cnt,
                                                const int* __restrict__ boff,
                                                int* __restrict__ rowptr) {
  const int t = threadIdx.x;
  const int i = blockIdx.x * 256 + t;
  const int lane = t & 63, wid = t >> 6;
  int v = (i < NN) ? cnt[i] : 0;
  int inc = v;
  for (int off = 1; off < 64; off <<= 1) {
    int y = __shfl_up(inc, off);
    if (lane >= off) inc += y;
  }
  __shared__ int wsum[4], woff[4];
  if (lane == 63) wsum[wid] = inc;
  __syncthreads();
  if (t == 0) {
    int run = 0;
    for (int w = 0; w < 4; ++w) { woff[w] = run; run += wsum[w]; }
  }
  __syncthreads();
  if (i < NN) rowptr[i] = boff[blockIdx.x] + woff[wid] + inc - v;
}

// fill CSR with (src, weight) pairs; weight = dinv[src]*dinv[dst]
__global__ void k_fill(const int* __restrict__ src, const int* __restrict__ dst,
                       const float* __restrict__ dinv, const int* __restrict__ rowptr,
                       int* __restrict__ fill, int2* __restrict__ eidx2) {
  int e = blockIdx.x * blockDim.x + threadIdx.x;
  if (e >= NEDGE) return;
  const int d = dst[e];
  const int s = src[e];
  const int p = rowptr[d] + atomicAdd(&fill[d], 1);
  eidx2[p] = make_int2(s, __float_as_int(dinv[s] * dinv[d]));
}

// ---------------- all 4 weights: transpose + bf16 in one launch ----------------
__global__ __launch_bounds__(256) void k_wconv_all(
    const float* __restrict__ W1, const float* __restrict__ W2,
    const float* __restrict__ W3, const float* __restrict__ W4,
    unsigned short* __restrict__ Wt1, unsigned short* __restrict__ Wt2,
    unsigned short* __restrict__ Wt3, unsigned short* __restrict__ Wt4) {
  const int b = blockIdx.x;
  const int n = threadIdx.x;
  if (b < 128) {                       // W1: K=128,N=256
    Wt1[(size_t)n * 128 + b] = f2bf(W1[(size_t)b * 256 + n]);
  } else if (b < 384) {                // W2: K=256,N=256
    const int k = b - 128;
    Wt2[(size_t)n * 256 + k] = f2bf(W2[(size_t)k * 256 + n]);
  } else if (b < 640) {                // W3
    const int k = b - 384;
    Wt3[(size_t)n * 256 + k] = f2bf(W3[(size_t)k * 256 + n]);
  } else {                             // W4: K=256,N=128
    const int k = b - 640;
    if (n < 128) Wt4[(size_t)n * 256 + k] = f2bf(W4[(size_t)k * 128 + n]);
  }
}

// ---------------- x -> bf16 ----------------
__global__ void k_xconv(const float* __restrict__ in, unsigned short* __restrict__ out) {
  const int i = blockIdx.x * blockDim.x + threadIdx.x;  // one float4 per thread
  if (i >= NN * 32) return;
  float4 v = reinterpret_cast<const float4*>(in)[i];
  ushort4 o; o.x = f2bf(v.x); o.y = f2bf(v.y); o.z = f2bf(v.z); o.w = f2bf(v.w);
  reinterpret_cast<ushort4*>(out)[i] = o;
}

// ---------------- gather aggregation (CSR), multi-node waves ----------------
// NPW nodes per wave; each node served by LPN=64/NPW lanes, 8 elems (16B) per lane.
// MODE 0: bf16 out.  MODE 1: fp32 out with fused bias+LN (F=128 final layer).
template<int F, int NPW, int MODE>
__global__ __launch_bounds__(256) void k_gather(
    const int* __restrict__ rowptr, const int2* __restrict__ eidx2,
    const float* __restrict__ dinv, const unsigned short* __restrict__ h,
    void* __restrict__ outv, const float* __restrict__ bias,
    const float* __restrict__ gamma, const float* __restrict__ beta) {
  constexpr int LPN = 64 / NPW;
  static_assert(F / LPN == 8, "16B per lane");
  const int tid = threadIdx.x;
  const int lane = tid & 63;
  const int sub = lane / LPN;
  const int slane = lane % LPN;
  const int n = blockIdx.x * (4 * NPW) + (tid >> 6) * NPW + sub;
  const bool valid = n < NN;

  int e = 0, end = 0;
  float dn = 0.f;
  if (valid) {
    dn = dinv[n];
    e = rowptr[n];
    end = rowptr[n + 1];
  }

  float acc[8];
  ushort8v r0 = (ushort8v)0, r1 = (ushort8v)0;
  if (valid) r0 = *reinterpret_cast<const ushort8v*>(h + (size_t)n * F + slane * 8);
  const float sw = dn * dn;
#pragma unroll
  for (int j = 0; j < 8; ++j) acc[j] = bf2f(r0[j]) * sw;
  r0 = (ushort8v)0;

  while (__ballot(e < end)) {
    float w0 = 0.f, w1 = 0.f;
    if (e < end) {
      const int2 p = eidx2[e];
      w0 = __int_as_float(p.y);
      r0 = *reinterpret_cast<const ushort8v*>(h + (size_t)p.x * F + slane * 8);
    }
    if (e + 1 < end) {
      const int2 p = eidx2[e + 1];
      w1 = __int_as_float(p.y);
      r1 = *reinterpret_cast<const ushort8v*>(h + (size_t)p.x * F + slane * 8);
    }
#pragma unroll
    for (int j = 0; j < 8; ++j)
      acc[j] += w0 * bf2f(r0[j]) + w1 * bf2f(r1[j]);
    e += 2;
  }

  if (!valid) return;

  if constexpr (MODE == 0) {
    ushort8v o;
#pragma unroll
    for (int j = 0; j < 8; ++j) o[j] = f2bf(acc[j]);
    *reinterpret_cast<ushort8v*>((unsigned short*)outv + (size_t)n * F + slane * 8) = o;
  } else {
    // fused bias + LN over F=128 (16 lanes per row)
    const float4 b0 = *reinterpret_cast<const float4*>(bias + slane * 8);
    const float4 b1 = *reinterpret_cast<const float4*>(bias + slane * 8 + 4);
    acc[0] += b0.x; acc[1] += b0.y; acc[2] += b0.z; acc[3] += b0.w;
    acc[4] += b1.x; acc[5] += b1.y; acc[6] += b1.z; acc[7] += b1.w;
    float s = 0.f, q = 0.f;
#pragma unroll
    for (int j = 0; j < 8; ++j) { s += acc[j]; q = fmaf(acc[j], acc[j], q); }
#pragma unroll
    for (int off = 1; off < 16; off <<= 1) {
      s += __shfl_xor(s, off);
      q += __shfl_xor(q, off);
    }
    const float mean = s * (1.0f / 128.0f);
    const float var = q * (1.0f / 128.0f) - mean * mean;
    const float inv = rsqrtf(var + LN_EPS);
    const float4 g0 = *reinterpret_cast<const float4*>(gamma + slane * 8);
    const float4 g1 = *reinterpret_cast<const float4*>(gamma + slane * 8 + 4);
    const float4 e0 = *reinterpret_cast<const float4*>(beta + slane * 8);
    const float4 e1 = *reinterpret_cast<const float4*>(beta + slane * 8 + 4);
    float4 o0, o1;
    o0.x = (acc[0] - mean) * inv * g0.x + e0.x;
    o0.y = (acc[1] - mean) * inv * g0.y + e0.y;
    o0.z = (acc[2] - mean) * inv * g0.z + e0.z;
    o0.w = (acc[3] - mean) * inv * g0.w + e0.w;
    o1.x = (acc[4] - mean) * inv * g1.x + e1.x;
    o1.y = (acc[5] - mean) * inv * g1.y + e1.y;
    o1.z = (acc[6] - mean) * inv * g1.z + e1.z;
    o1.w = (acc[7] - mean) * inv * g1.w + e1.w;
    float* out = (float*)outv + (size_t)n * 128 + slane * 8;
    *reinterpret_cast<float4*>(out) = o0;
    *reinterpret_cast<float4*>(out + 4) = o1;
  }
}

// ---------------- MFMA GEMM, optional fused bias+LN+ReLU epilogue ----------------
// block: 4 waves, 64 rows; wave w owns cols [w*N/4, (w+1)*N/4)
template<int K, int N, bool LNFUSE>
__global__ __launch_bounds__(256) void k_mgemm(const unsigned short* __restrict__ A,
                                               const unsigned short* __restrict__ Bt,
                                               const float* __restrict__ bias,
                                               const float* __restrict__ gamma,
                                               const float* __restrict__ beta,
                                               unsigned short* __restrict__ out) {
  constexpr int NT = N / 64;   // 16-col tiles per wave
  constexpr int KS = K / 32;   // k-steps
  __shared__ __align__(16) unsigned short As[64 * K];

  const int tid = threadIdx.x;
  const int lane = tid & 63;
  const int w = tid >> 6;
  const int m0 = blockIdx.x * 64;

  // stage A tile into LDS with XOR swizzle on 16B slots
#pragma unroll
  for (int i = 0; i < KS; ++i) {
    const int o = (i * 256 + tid) * 16;
    const int row = o / (2 * K);
    const int inb = o % (2 * K);
    uint4 val = *reinterpret_cast<const uint4*>(
        (const char*)A + (size_t)(m0 + row) * (2 * K) + inb);
    const int dsto = o ^ ((row & 7) << 4);
    *reinterpret_cast<uint4*>((char*)As + dsto) = val;
  }
  __syncthreads();

  f32x4 acc[4][NT];
#pragma unroll
  for (int mt = 0; mt < 4; ++mt)
#pragma unroll
    for (int nt = 0; nt < NT; ++nt) acc[mt][nt] = (f32x4){0.f, 0.f, 0.f, 0.f};

  const int nw0 = w * (N / 4);
  const int arow = lane & 15;
  const int kgrp = (lane >> 4) * 8;

  for (int ks = 0; ks < KS; ++ks) {
    bf16x8 af[4];
#pragma unroll
    for (int mt = 0; mt < 4; ++mt) {
      const int r = mt * 16 + arow;
      int boff = (r * K + ks * 32 + kgrp) * 2;
      boff ^= (r & 7) << 4;
      af[mt] = *reinterpret_cast<const bf16x8*>((const char*)As + boff);
    }
    bf16x8 bfr[NT];
#pragma unroll
    for (int nt = 0; nt < NT; ++nt) {
      const int n = nw0 + nt * 16 + arow;
      bfr[nt] = *reinterpret_cast<const bf16x8*>(Bt + (size_t)n * K + ks * 32 + kgrp);
    }
#pragma unroll
    for (int mt = 0; mt < 4; ++mt)
#pragma unroll
      for (int nt = 0; nt < NT; ++nt)
        acc[mt][nt] = __builtin_amdgcn_mfma_f32_16x16x32_bf16(af[mt], bfr[nt], acc[mt][nt], 0, 0, 0);
  }

  const int g = lane >> 4;       // 16-lane group: rows g*4..g*4+3 (+16*mt)
  const int cl = lane & 15;      // col within 16-tile

  if constexpr (LNFUSE) {
    float gv[NT], bev[NT];
#pragma unroll
    for (int nt = 0; nt < NT; ++nt) {
      const int c = nw0 + nt * 16 + cl;
      const float bv = bias[c];
      gv[nt] = gamma[c];
      bev[nt] = beta[c];
#pragma unroll
      for (int mt = 0; mt < 4; ++mt)
#pragma unroll
        for (int reg = 0; reg < 4; ++reg) acc[mt][nt][reg] += bv;
    }
    __shared__ float sS[4][64];
    __shared__ float sQ[4][64];
    float ps[4][4], pq[4][4];
#pragma unroll
    for (int mt = 0; mt < 4; ++mt) {
#pragma unroll
      for (int reg = 0; reg < 4; ++reg) {
        float s = 0.f, q = 0.f;
#pragma unroll
        for (int nt = 0; nt < NT; ++nt) {
          const float v = acc[mt][nt][reg];
          s += v; q = fmaf(v, v, q);
        }
#pragma unroll
        for (int off = 1; off < 16; off <<= 1) {
          s += __shfl_xor(s, off);
          q += __shfl_xor(q, off);
        }
        ps[mt][reg] = s; pq[mt][reg] = q;
      }
    }
    if (cl == 0) {
#pragma unroll
      for (int mt = 0; mt < 4; ++mt)
#pragma unroll
        for (int reg = 0; reg < 4; ++reg) {
          sS[w][mt * 16 + g * 4 + reg] = ps[mt][reg];
          sQ[w][mt * 16 + g * 4 + reg] = pq[mt][reg];
        }
    }
    __syncthreads();
#pragma unroll
    for (int mt = 0; mt < 4; ++mt) {
#pragma unroll
      for (int reg = 0; reg < 4; ++reg) {
        const int rr = mt * 16 + g * 4 + reg;
        const int r = m0 + rr;
        const float S = sS[0][rr] + sS[1][rr] + sS[2][rr] + sS[3][rr];
        const float Q = sQ[0][rr] + sQ[1][rr] + sQ[2][rr] + sQ[3][rr];
        const float mean = S * (1.0f / N);
        const float var = Q * (1.0f / N) - mean * mean;
        const float inv = rsqrtf(var + LN_EPS);
        if (r < NN) {
#pragma unroll
          for (int nt = 0; nt < NT; ++nt) {
            const int c = nw0 + nt * 16 + cl;
            const float o = fmaxf((acc[mt][nt][reg] - mean) * inv * gv[nt] + bev[nt], 0.f);
            out[(size_t)r * N + c] = f2bf(o);
          }
        }
      }
    }
  } else {
#pragma unroll
    for (int mt = 0; mt < 4; ++mt) {
#pragma unroll
      for (int nt = 0; nt < NT; ++nt) {
        const int c = nw0 + nt * 16 + cl;
#pragma unroll
        for (int reg = 0; reg < 4; ++reg) {
          const int r = m0 + mt * 16 + g * 4 + reg;
          if (r < NN) out[(size_t)r * N + c] = f2bf(acc[mt][nt][reg]);
        }
      }
    }
  }
}

extern "C" void kernel_launch(void* const* d_in, const int* in_sizes, int n_in,
                              void* d_out, int out_size, void* d_ws, size_t ws_size,
                              hipStream_t stream) {
  const float* x   = (const float*)d_in[0];
  const int*   ei  = (const int*)d_in[1];
  const float* W1  = (const float*)d_in[2];
  const float* b1  = (const float*)d_in[3];
  const float* W2  = (const float*)d_in[4];
  const float* b2  = (const float*)d_in[5];
  const float* W3  = (const float*)d_in[6];
  const float* b3  = (const float*)d_in[7];
  const float* W4  = (const float*)d_in[8];
  const float* b4  = (const float*)d_in[9];
  const float* g1  = (const float*)d_in[10];
  const float* be1 = (const float*)d_in[11];
  const float* g2  = (const float*)d_in[12];
  const float* be2 = (const float*)d_in[13];
  const float* g3  = (const float*)d_in[14];
  const float* be3 = (const float*)d_in[15];
  const float* g4  = (const float*)d_in[16];
  const float* be4 = (const float*)d_in[17];

  const int* src = ei;
  const int* dst = ei + NEDGE;

  char* ws = (char*)d_ws;
  int*   cnt    = (int*)(ws + 0);              // NN ints (reserve 204800)
  int*   fill   = (int*)(ws + 204800);         // NN ints
  int*   rowptr = (int*)(ws + 409600);         // NN+1 ints
  float* dinv   = (float*)(ws + 614400);       // NN floats
  int*   bsum   = (int*)(ws + 819200);         // NB ints
  int*   boff   = (int*)(ws + 823296);         // NB ints
  int2*  eidx2  = (int2*)(ws + 827392);        // NEDGE int2 (3.2MB)
  unsigned short* Wt1 = (unsigned short*)(ws + 4030464);   // 256x128
  unsigned short* Wt2 = (unsigned short*)(ws + 4096000);   // 256x256
  unsigned short* Wt3 = (unsigned short*)(ws + 4227072);   // 256x256
  unsigned short* Wt4 = (unsigned short*)(ws + 4358144);   // 128x256
  unsigned short* xB  = (unsigned short*)(ws + 4423680);   // MPAD x 128 bf16
  unsigned short* aggB = (unsigned short*)(ws + 17235968); // MPAD x 256 bf16
  unsigned short* hB   = (unsigned short*)(ws + 42860544); // MPAD x 256 bf16
  unsigned short* t4B  = (unsigned short*)(ws + 68485120); // MPAD x 128 bf16
  float* out = (float*)d_out;

  const int MB = (NN + 63) / 64;  // 782

  // CSR + dinv + weight/x conversion
  hipMemsetAsync(cnt, 0, 409600, stream);  // cnt + fill
  k_count<<<(NEDGE + 255) / 256, 256, 0, stream>>>(dst, cnt);
  k_bsum<<<NB, 256, 0, stream>>>(cnt, bsum, dinv);
  k_bscan<<<1, 256, 0, stream>>>(bsum, boff, rowptr);
  k_bapply<<<NB, 256, 0, stream>>>(cnt, boff, rowptr);
  k_fill<<<(NEDGE + 255) / 256, 256, 0, stream>>>(src, dst, dinv, rowptr, fill, eidx2);
  k_wconv_all<<<896, 256, 0, stream>>>(W1, W2, W3, W4, Wt1, Wt2, Wt3, Wt4);
  k_xconv<<<(NN * 32 + 255) / 256, 256, 0, stream>>>(x, xB);

  // ---- Layer 1 ----
  k_gather<128, 4, 0><<<(NN + 15) / 16, 256, 0, stream>>>(rowptr, eidx2, dinv, xB, aggB, nullptr, nullptr, nullptr);
  k_mgemm<128, 256, true><<<MB, 256, 0, stream>>>(aggB, Wt1, b1, g1, be1, hB);

  // ---- Layer 2 ----
  k_gather<256, 2, 0><<<(NN + 7) / 8, 256, 0, stream>>>(rowptr, eidx2, dinv, hB, aggB, nullptr, nullptr, nullptr);
  k_mgemm<256, 256, true><<<MB, 256, 0, stream>>>(aggB, Wt2, b2, g2, be2, hB);

  // ---- Layer 3 ----
  k_gather<256, 2, 0><<<(NN + 7) / 8, 256, 0, stream>>>(rowptr, eidx2, dinv, hB, aggB, nullptr, nullptr, nullptr);
  k_mgemm<256, 256, true><<<MB, 256, 0, stream>>>(aggB, Wt3, b3, g3, be3, hB);

  // ---- Layer 4: transform (256->128) -> gather + fused bias+LN into d_out ----
  k_mgemm<256, 128, false><<<MB, 256, 0, stream>>>(hB, Wt4, nullptr, nullptr, nullptr, t4B);
  k_gather<128, 4, 1><<<(NN + 15) / 16, 256, 0, stream>>>(rowptr, eidx2, dinv, t4B, out, b4, g4, be4);
}

// Round 6
// 285.254 us; speedup vs baseline: 17.0775x; 1.0441x over previous
//
#include <hip/hip_runtime.h>

#define NN 50000
#define NEDGE 400000
#define MPAD 50048
#define NB 196  // scan blocks: 196*256 = 50176 >= NN
constexpr float LN_EPS = 1e-5f;

typedef __attribute__((ext_vector_type(8))) short bf16x8;
typedef __attribute__((ext_vector_type(4))) float f32x4;
typedef __attribute__((ext_vector_type(8))) unsigned short ushort8v;

__device__ __forceinline__ unsigned short f2bf(float f) {  // RNE
  unsigned int u = __float_as_uint(f);
  u += 0x7FFFu + ((u >> 16) & 1u);
  return (unsigned short)(u >> 16);
}
__device__ __forceinline__ float bf2f(unsigned short u) {
  return __uint_as_float(((unsigned int)u) << 16);
}

// ---------------- prep: weight transpose->bf16, x->bf16, zero cnt (one launch) ----------------
__global__ __launch_bounds__(256) void k_prep(
    const float* __restrict__ W1, const float* __restrict__ W2,
    const float* __restrict__ W3, const float* __restrict__ W4,
    unsigned short* __restrict__ Wt1, unsigned short* __restrict__ Wt2,
    unsigned short* __restrict__ Wt3, unsigned short* __restrict__ Wt4,
    const float* __restrict__ x, unsigned short* __restrict__ xB,
    int* __restrict__ cnt) {
  const int b = blockIdx.x;
  const int n = threadIdx.x;
  if (b < 128) {                       // W1: K=128,N=256
    Wt1[(size_t)n * 128 + b] = f2bf(W1[(size_t)b * 256 + n]);
  } else if (b < 384) {                // W2: K=256,N=256
    const int k = b - 128;
    Wt2[(size_t)n * 256 + k] = f2bf(W2[(size_t)k * 256 + n]);
  } else if (b < 640) {                // W3
    const int k = b - 384;
    Wt3[(size_t)n * 256 + k] = f2bf(W3[(size_t)k * 256 + n]);
  } else if (b < 896) {                // W4: K=256,N=128
    const int k = b - 640;
    if (n < 128) Wt4[(size_t)n * 256 + k] = f2bf(W4[(size_t)k * 128 + n]);
  } else if (b < 7146) {               // x -> bf16, one float4 per thread
    const int i = (b - 896) * 256 + n;
    float4 v = reinterpret_cast<const float4*>(x)[i];
    ushort4 o; o.x = f2bf(v.x); o.y = f2bf(v.y); o.z = f2bf(v.z); o.w = f2bf(v.w);
    reinterpret_cast<ushort4*>(xB)[i] = o;
  } else {                             // zero cnt
    const int i = (b - 7146) * 256 + n;
    if (i < NN) cnt[i] = 0;
  }
}

// ---------------- CSR build ----------------
__global__ void k_count(const int* __restrict__ dst, int* __restrict__ cnt) {
  int e = blockIdx.x * blockDim.x + threadIdx.x;
  if (e < NEDGE) atomicAdd(&cnt[dst[e]], 1);
}

// block partial sums of cnt (+ fused dinv)
__global__ __launch_bounds__(256) void k_bsum(const int* __restrict__ cnt,
                                              int* __restrict__ bsum,
                                              float* __restrict__ dinv) {
  const int i = blockIdx.x * 256 + threadIdx.x;
  int v = 0;
  if (i < NN) {
    v = cnt[i];
    dinv[i] = rsqrtf((float)v + 1.0f);
  }
  int s = v;
#pragma unroll
  for (int off = 32; off > 0; off >>= 1) s += __shfl_xor(s, off);
  __shared__ int wsum[4];
  if ((threadIdx.x & 63) == 0) wsum[threadIdx.x >> 6] = s;
  __syncthreads();
  if (threadIdx.x == 0) bsum[blockIdx.x] = wsum[0] + wsum[1] + wsum[2] + wsum[3];
}

// rowptr build: every block scans bsum (196 entries) in LDS, then per-block scan of cnt.
// Writes rowptr AND a mutable cursor copy for k_fill.
__global__ __launch_bounds__(256) void k_bapply(const int* __restrict__ cnt,
                                                const int* __restrict__ bsum,
                                                int* __restrict__ rowptr,
                                                int* __restrict__ cursor) {
  __shared__ int sOff[NB];
  __shared__ int wsum[4], woff[4];
  const int t = threadIdx.x;
  const int lane = t & 63, wid = t >> 6;

  // exclusive scan of bsum into sOff
  {
    int v = (t < NB) ? bsum[t] : 0;
    int inc = v;
    for (int off = 1; off < 64; off <<= 1) {
      int y = __shfl_up(inc, off);
      if (lane >= off) inc += y;
    }
    if (lane == 63) wsum[wid] = inc;
    __syncthreads();
    if (t == 0) {
      int run = 0;
      for (int w = 0; w < 4; ++w) { woff[w] = run; run += wsum[w]; }
    }
    __syncthreads();
    if (t < NB) sOff[t] = woff[wid] + inc - v;
  }
  __syncthreads();

  // per-block exclusive scan of cnt chunk
  const int i = blockIdx.x * 256 + t;
  int v = (i < NN) ? cnt[i] : 0;
  int inc = v;
  for (int off = 1; off < 64; off <<= 1) {
    int y = __shfl_up(inc, off);
    if (lane >= off) inc += y;
  }
  if (lane == 63) wsum[wid] = inc;
  __syncthreads();
  if (t == 0) {
    int run = 0;
    for (int w = 0; w < 4; ++w) { woff[w] = run; run += wsum[w]; }
  }
  __syncthreads();
  if (i < NN) {
    const int rp = sOff[blockIdx.x] + woff[wid] + inc - v;
    rowptr[i] = rp;
    cursor[i] = rp;
  }
  if (blockIdx.x == 0 && t == 0) rowptr[NN] = NEDGE;
}

// fill CSR with (src, weight) pairs; weight = dinv[src]*dinv[dst]
__global__ void k_fill(const int* __restrict__ src, const int* __restrict__ dst,
                       const float* __restrict__ dinv, int* __restrict__ cursor,
                       int2* __restrict__ eidx2) {
  int e = blockIdx.x * blockDim.x + threadIdx.x;
  if (e >= NEDGE) return;
  const int d = dst[e];
  const int s = src[e];
  const int p = atomicAdd(&cursor[d], 1);
  eidx2[p] = make_int2(s, __float_as_int(dinv[s] * dinv[d]));
}

// ---------------- gather aggregation (CSR), multi-node waves, 4-wide unroll ----------------
// NPW nodes per wave; each node served by LPN=64/NPW lanes, 8 elems (16B) per lane.
// MODE 0: bf16 out.  MODE 1: fp32 out with fused bias+LN (F=128 final layer).
template<int F, int NPW, int MODE>
__global__ __launch_bounds__(256) void k_gather(
    const int* __restrict__ rowptr, const int2* __restrict__ eidx2,
    const float* __restrict__ dinv, const unsigned short* __restrict__ h,
    void* __restrict__ outv, const float* __restrict__ bias,
    const float* __restrict__ gamma, const float* __restrict__ beta) {
  constexpr int LPN = 64 / NPW;
  static_assert(F / LPN == 8, "16B per lane");
  const int tid = threadIdx.x;
  const int lane = tid & 63;
  const int sub = lane / LPN;
  const int slane = lane % LPN;
  const int n = blockIdx.x * (4 * NPW) + (tid >> 6) * NPW + sub;
  const bool valid = n < NN;

  int e = 0, end = 0;
  float dn = 0.f;
  if (valid) {
    dn = dinv[n];
    e = rowptr[n];
    end = rowptr[n + 1];
  }

  float acc[8];
  ushort8v r0 = (ushort8v)0, r1 = (ushort8v)0, r2 = (ushort8v)0, r3 = (ushort8v)0;
  if (valid) r0 = *reinterpret_cast<const ushort8v*>(h + (size_t)n * F + slane * 8);
  const float sw = dn * dn;
#pragma unroll
  for (int j = 0; j < 8; ++j) acc[j] = bf2f(r0[j]) * sw;
  r0 = (ushort8v)0;

  while (__ballot(e < end)) {
    float w0 = 0.f, w1 = 0.f, w2 = 0.f, w3 = 0.f;
    if (e < end) {
      const int2 p = eidx2[e];
      w0 = __int_as_float(p.y);
      r0 = *reinterpret_cast<const ushort8v*>(h + (size_t)p.x * F + slane * 8);
    }
    if (e + 1 < end) {
      const int2 p = eidx2[e + 1];
      w1 = __int_as_float(p.y);
      r1 = *reinterpret_cast<const ushort8v*>(h + (size_t)p.x * F + slane * 8);
    }
    if (e + 2 < end) {
      const int2 p = eidx2[e + 2];
      w2 = __int_as_float(p.y);
      r2 = *reinterpret_cast<const ushort8v*>(h + (size_t)p.x * F + slane * 8);
    }
    if (e + 3 < end) {
      const int2 p = eidx2[e + 3];
      w3 = __int_as_float(p.y);
      r3 = *reinterpret_cast<const ushort8v*>(h + (size_t)p.x * F + slane * 8);
    }
#pragma unroll
    for (int j = 0; j < 8; ++j)
      acc[j] += w0 * bf2f(r0[j]) + w1 * bf2f(r1[j]) + w2 * bf2f(r2[j]) + w3 * bf2f(r3[j]);
    e += 4;
  }

  if (!valid) return;

  if constexpr (MODE == 0) {
    ushort8v o;
#pragma unroll
    for (int j = 0; j < 8; ++j) o[j] = f2bf(acc[j]);
    *reinterpret_cast<ushort8v*>((unsigned short*)outv + (size_t)n * F + slane * 8) = o;
  } else {
    // fused bias + LN over F=128 (16 lanes per row)
    const float4 b0 = *reinterpret_cast<const float4*>(bias + slane * 8);
    const float4 b1 = *reinterpret_cast<const float4*>(bias + slane * 8 + 4);
    acc[0] += b0.x; acc[1] += b0.y; acc[2] += b0.z; acc[3] += b0.w;
    acc[4] += b1.x; acc[5] += b1.y; acc[6] += b1.z; acc[7] += b1.w;
    float s = 0.f, q = 0.f;
#pragma unroll
    for (int j = 0; j < 8; ++j) { s += acc[j]; q = fmaf(acc[j], acc[j], q); }
#pragma unroll
    for (int off = 1; off < 16; off <<= 1) {
      s += __shfl_xor(s, off);
      q += __shfl_xor(q, off);
    }
    const float mean = s * (1.0f / 128.0f);
    const float var = q * (1.0f / 128.0f) - mean * mean;
    const float inv = rsqrtf(var + LN_EPS);
    const float4 g0 = *reinterpret_cast<const float4*>(gamma + slane * 8);
    const float4 g1 = *reinterpret_cast<const float4*>(gamma + slane * 8 + 4);
    const float4 e0 = *reinterpret_cast<const float4*>(beta + slane * 8);
    const float4 e1 = *reinterpret_cast<const float4*>(beta + slane * 8 + 4);
    float4 o0, o1;
    o0.x = (acc[0] - mean) * inv * g0.x + e0.x;
    o0.y = (acc[1] - mean) * inv * g0.y + e0.y;
    o0.z = (acc[2] - mean) * inv * g0.z + e0.z;
    o0.w = (acc[3] - mean) * inv * g0.w + e0.w;
    o1.x = (acc[4] - mean) * inv * g1.x + e1.x;
    o1.y = (acc[5] - mean) * inv * g1.y + e1.y;
    o1.z = (acc[6] - mean) * inv * g1.z + e1.z;
    o1.w = (acc[7] - mean) * inv * g1.w + e1.w;
    float* out = (float*)outv + (size_t)n * 128 + slane * 8;
    *reinterpret_cast<float4*>(out) = o0;
    *reinterpret_cast<float4*>(out + 4) = o1;
  }
}

// ---------------- MFMA GEMM, optional fused bias+LN+ReLU epilogue ----------------
// block: 4 waves, 64 rows; wave w owns cols [w*N/4, (w+1)*N/4)
template<int K, int N, bool LNFUSE>
__global__ __launch_bounds__(256) void k_mgemm(const unsigned short* __restrict__ A,
                                               const unsigned short* __restrict__ Bt,
                                               const float* __restrict__ bias,
                                               const float* __restrict__ gamma,
                                               const float* __restrict__ beta,
                                               unsigned short* __restrict__ out) {
  constexpr int NT = N / 64;   // 16-col tiles per wave
  constexpr int KS = K / 32;   // k-steps
  __shared__ __align__(16) unsigned short As[64 * K];

  const int tid = threadIdx.x;
  const int lane = tid & 63;
  const int w = tid >> 6;
  const int m0 = blockIdx.x * 64;

  // stage A tile into LDS with XOR swizzle on 16B slots
#pragma unroll
  for (int i = 0; i < KS; ++i) {
    const int o = (i * 256 + tid) * 16;
    const int row = o / (2 * K);
    const int inb = o % (2 * K);
    uint4 val = *reinterpret_cast<const uint4*>(
        (const char*)A + (size_t)(m0 + row) * (2 * K) + inb);
    const int dsto = o ^ ((row & 7) << 4);
    *reinterpret_cast<uint4*>((char*)As + dsto) = val;
  }
  __syncthreads();

  f32x4 acc[4][NT];
#pragma unroll
  for (int mt = 0; mt < 4; ++mt)
#pragma unroll
    for (int nt = 0; nt < NT; ++nt) acc[mt][nt] = (f32x4){0.f, 0.f, 0.f, 0.f};

  const int nw0 = w * (N / 4);
  const int arow = lane & 15;
  const int kgrp = (lane >> 4) * 8;

  for (int ks = 0; ks < KS; ++ks) {
    bf16x8 af[4];
#pragma unroll
    for (int mt = 0; mt < 4; ++mt) {
      const int r = mt * 16 + arow;
      int boff = (r * K + ks * 32 + kgrp) * 2;
      boff ^= (r & 7) << 4;
      af[mt] = *reinterpret_cast<const bf16x8*>((const char*)As + boff);
    }
    bf16x8 bfr[NT];
#pragma unroll
    for (int nt = 0; nt < NT; ++nt) {
      const int n = nw0 + nt * 16 + arow;
      bfr[nt] = *reinterpret_cast<const bf16x8*>(Bt + (size_t)n * K + ks * 32 + kgrp);
    }
#pragma unroll
    for (int mt = 0; mt < 4; ++mt)
#pragma unroll
      for (int nt = 0; nt < NT; ++nt)
        acc[mt][nt] = __builtin_amdgcn_mfma_f32_16x16x32_bf16(af[mt], bfr[nt], acc[mt][nt], 0, 0, 0);
  }

  const int g = lane >> 4;       // 16-lane group: rows g*4..g*4+3 (+16*mt)
  const int cl = lane & 15;      // col within 16-tile

  if constexpr (LNFUSE) {
    float gv[NT], bev[NT];
#pragma unroll
    for (int nt = 0; nt < NT; ++nt) {
      const int c = nw0 + nt * 16 + cl;
      const float bv = bias[c];
      gv[nt] = gamma[c];
      bev[nt] = beta[c];
#pragma unroll
      for (int mt = 0; mt < 4; ++mt)
#pragma unroll
        for (int reg = 0; reg < 4; ++reg) acc[mt][nt][reg] += bv;
    }
    __shared__ float sS[4][64];
    __shared__ float sQ[4][64];
    float ps[4][4], pq[4][4];
#pragma unroll
    for (int mt = 0; mt < 4; ++mt) {
#pragma unroll
      for (int reg = 0; reg < 4; ++reg) {
        float s = 0.f, q = 0.f;
#pragma unroll
        for (int nt = 0; nt < NT; ++nt) {
          const float v = acc[mt][nt][reg];
          s += v; q = fmaf(v, v, q);
        }
#pragma unroll
        for (int off = 1; off < 16; off <<= 1) {
          s += __shfl_xor(s, off);
          q += __shfl_xor(q, off);
        }
        ps[mt][reg] = s; pq[mt][reg] = q;
      }
    }
    if (cl == 0) {
#pragma unroll
      for (int mt = 0; mt < 4; ++mt)
#pragma unroll
        for (int reg = 0; reg < 4; ++reg) {
          sS[w][mt * 16 + g * 4 + reg] = ps[mt][reg];
          sQ[w][mt * 16 + g * 4 + reg] = pq[mt][reg];
        }
    }
    __syncthreads();
#pragma unroll
    for (int mt = 0; mt < 4; ++mt) {
#pragma unroll
      for (int reg = 0; reg < 4; ++reg) {
        const int rr = mt * 16 + g * 4 + reg;
        const int r = m0 + rr;
        const float S = sS[0][rr] + sS[1][rr] + sS[2][rr] + sS[3][rr];
        const float Q = sQ[0][rr] + sQ[1][rr] + sQ[2][rr] + sQ[3][rr];
        const float mean = S * (1.0f / N);
        const float var = Q * (1.0f / N) - mean * mean;
        const float inv = rsqrtf(var + LN_EPS);
        if (r < NN) {
#pragma unroll
          for (int nt = 0; nt < NT; ++nt) {
            const int c = nw0 + nt * 16 + cl;
            const float o = fmaxf((acc[mt][nt][reg] - mean) * inv * gv[nt] + bev[nt], 0.f);
            out[(size_t)r * N + c] = f2bf(o);
          }
        }
      }
    }
  } else {
#pragma unroll
    for (int mt = 0; mt < 4; ++mt) {
#pragma unroll
      for (int nt = 0; nt < NT; ++nt) {
        const int c = nw0 + nt * 16 + cl;
#pragma unroll
        for (int reg = 0; reg < 4; ++reg) {
          const int r = m0 + mt * 16 + g * 4 + reg;
          if (r < NN) out[(size_t)r * N + c] = f2bf(acc[mt][nt][reg]);
        }
      }
    }
  }
}

extern "C" void kernel_launch(void* const* d_in, const int* in_sizes, int n_in,
                              void* d_out, int out_size, void* d_ws, size_t ws_size,
                              hipStream_t stream) {
  const float* x   = (const float*)d_in[0];
  const int*   ei  = (const int*)d_in[1];
  const float* W1  = (const float*)d_in[2];
  const float* b1  = (const float*)d_in[3];
  const float* W2  = (const float*)d_in[4];
  const float* b2  = (const float*)d_in[5];
  const float* W3  = (const float*)d_in[6];
  const float* b3  = (const float*)d_in[7];
  const float* W4  = (const float*)d_in[8];
  const float* b4  = (const float*)d_in[9];
  const float* g1  = (const float*)d_in[10];
  const float* be1 = (const float*)d_in[11];
  const float* g2  = (const float*)d_in[12];
  const float* be2 = (const float*)d_in[13];
  const float* g3  = (const float*)d_in[14];
  const float* be3 = (const float*)d_in[15];
  const float* g4  = (const float*)d_in[16];
  const float* be4 = (const float*)d_in[17];

  const int* src = ei;
  const int* dst = ei + NEDGE;

  char* ws = (char*)d_ws;
  int*   cnt    = (int*)(ws + 0);              // NN ints
  int*   cursor = (int*)(ws + 204800);         // NN ints
  int*   rowptr = (int*)(ws + 409600);         // NN+1 ints
  float* dinv   = (float*)(ws + 614400);       // NN floats
  int*   bsum   = (int*)(ws + 819200);         // NB ints
  int2*  eidx2  = (int2*)(ws + 827392);        // NEDGE int2 (3.2MB)
  unsigned short* Wt1 = (unsigned short*)(ws + 4030464);   // 256x128
  unsigned short* Wt2 = (unsigned short*)(ws + 4096000);   // 256x256
  unsigned short* Wt3 = (unsigned short*)(ws + 4227072);   // 256x256
  unsigned short* Wt4 = (unsigned short*)(ws + 4358144);   // 128x256
  unsigned short* xB  = (unsigned short*)(ws + 4423680);   // MPAD x 128 bf16
  unsigned short* aggB = (unsigned short*)(ws + 17235968); // MPAD x 256 bf16
  unsigned short* hB   = (unsigned short*)(ws + 42860544); // MPAD x 256 bf16
  unsigned short* t4B  = (unsigned short*)(ws + 68485120); // MPAD x 128 bf16
  float* out = (float*)d_out;

  const int MB = (NN + 63) / 64;  // 782

  // prep (weights+x conversion, cnt zero) + CSR build
  k_prep<<<7342, 256, 0, stream>>>(W1, W2, W3, W4, Wt1, Wt2, Wt3, Wt4, x, xB, cnt);
  k_count<<<(NEDGE + 255) / 256, 256, 0, stream>>>(dst, cnt);
  k_bsum<<<NB, 256, 0, stream>>>(cnt, bsum, dinv);
  k_bapply<<<NB, 256, 0, stream>>>(cnt, bsum, rowptr, cursor);
  k_fill<<<(NEDGE + 255) / 256, 256, 0, stream>>>(src, dst, dinv, cursor, eidx2);

  // ---- Layer 1 ----
  k_gather<128, 4, 0><<<(NN + 15) / 16, 256, 0, stream>>>(rowptr, eidx2, dinv, xB, aggB, nullptr, nullptr, nullptr);
  k_mgemm<128, 256, true><<<MB, 256, 0, stream>>>(aggB, Wt1, b1, g1, be1, hB);

  // ---- Layer 2 ----
  k_gather<256, 2, 0><<<(NN + 7) / 8, 256, 0, stream>>>(rowptr, eidx2, dinv, hB, aggB, nullptr, nullptr, nullptr);
  k_mgemm<256, 256, true><<<MB, 256, 0, stream>>>(aggB, Wt2, b2, g2, be2, hB);

  // ---- Layer 3 ----
  k_gather<256, 2, 0><<<(NN + 7) / 8, 256, 0, stream>>>(rowptr, eidx2, dinv, hB, aggB, nullptr, nullptr, nullptr);
  k_mgemm<256, 256, true><<<MB, 256, 0, stream>>>(aggB, Wt3, b3, g3, be3, hB);

  // ---- Layer 4: transform (256->128) -> gather + fused bias+LN into d_out ----
  k_mgemm<256, 128, false><<<MB, 256, 0, stream>>>(hB, Wt4, nullptr, nullptr, nullptr, t4B);
  k_gather<128, 4, 1><<<(NN + 15) / 16, 256, 0, stream>>>(rowptr, eidx2, dinv, t4B, out, b4, g4, be4);
}